// Round 1
// baseline (1249.988 us; speedup 1.0000x reference)
//
#include <hip/hip_runtime.h>
#include <hip/hip_bf16.h>
#include <stdint.h>

#define NNODES 100000
#define NEDGES 600000
// IN = H = 128, OUT = 64, fixed by the problem.

// ---------------- small utility kernels ----------------

__global__ __launch_bounds__(256) void k_zero_stats(float* stats) {
    stats[threadIdx.x] = 0.0f;  // 256 floats: sum[128], sumsq[128]
}

__global__ __launch_bounds__(256) void k_copy(const float4* __restrict__ x,
                                              float4* __restrict__ buf, int n4) {
    int i = blockIdx.x * 256 + threadIdx.x;
    if (i < n4) buf[i] = x[i];
}

// one edge handled by 32 threads (4 floats each)
__global__ __launch_bounds__(256) void k_scatter(const int* __restrict__ ei,
                                                 const float4* __restrict__ x,
                                                 float* __restrict__ buf) {
    int tid = blockIdx.x * 256 + threadIdx.x;
    int e = tid >> 5, c = tid & 31;
    if (e >= NEDGES) return;
    int src = ei[e];
    int dst = ei[NEDGES + e];
    float4 v = x[(size_t)src * 32 + c];
    float* p = buf + (size_t)dst * 128 + c * 4;
    atomicAdd(p + 0, v.x);
    atomicAdd(p + 1, v.y);
    atomicAdd(p + 2, v.z);
    atomicAdd(p + 3, v.w);
}

// ---------------- GEMM1 + BN stats ----------------
// h1 = buf @ W1 + b1 ; stats[c] += sum over rows, stats[128+c] += sum of squares
__global__ __launch_bounds__(256) void k_gemm1(const float* __restrict__ A,
                                               const float* __restrict__ W,
                                               const float* __restrict__ b,
                                               float* __restrict__ h1,
                                               float* __restrict__ stats) {
    __shared__ float As[32][68];        // A-tile transposed [k][row], padded
    __shared__ float Ws[32][128];       // W-tile [k][col]
    __shared__ float Sred[2][16][128];  // per-rowgroup partial sum / sumsq

    int t = threadIdx.x;
    int tc = t & 15;        // col group: cols tc*8 .. tc*8+7
    int tr = t >> 4;        // row group: rows tr*4 .. tr*4+3
    int r0 = blockIdx.x * 64;

    float acc[4][8];
#pragma unroll
    for (int i = 0; i < 4; ++i)
#pragma unroll
        for (int j = 0; j < 8; ++j) acc[i][j] = 0.0f;

    for (int kc = 0; kc < 128; kc += 32) {
        // stage A tile (transposed), zero-fill rows past N
#pragma unroll
        for (int z = 0; z < 2; ++z) {
            int idx = t + z * 256;       // 0..511
            int row = idx >> 3;          // 0..63
            int k4 = (idx & 7) * 4;      // 0,4,..,28
            int gr = r0 + row;
            float4 v = make_float4(0.f, 0.f, 0.f, 0.f);
            if (gr < NNODES) v = *(const float4*)(A + (size_t)gr * 128 + kc + k4);
            As[k4 + 0][row] = v.x;
            As[k4 + 1][row] = v.y;
            As[k4 + 2][row] = v.z;
            As[k4 + 3][row] = v.w;
        }
        // stage W tile
#pragma unroll
        for (int z = 0; z < 4; ++z) {
            int idx = t + z * 256;       // 0..1023
            int k = idx >> 5;            // 0..31
            int c4 = (idx & 31) * 4;     // 0..124
            *(float4*)&Ws[k][c4] = *(const float4*)(W + (size_t)(kc + k) * 128 + c4);
        }
        __syncthreads();
#pragma unroll 4
        for (int k = 0; k < 32; ++k) {
            float4 a = *(const float4*)&As[k][tr * 4];
            float4 w0 = *(const float4*)&Ws[k][tc * 8];
            float4 w1 = *(const float4*)&Ws[k][tc * 8 + 4];
            float av[4] = {a.x, a.y, a.z, a.w};
            float wv[8] = {w0.x, w0.y, w0.z, w0.w, w1.x, w1.y, w1.z, w1.w};
#pragma unroll
            for (int i = 0; i < 4; ++i)
#pragma unroll
                for (int j = 0; j < 8; ++j) acc[i][j] = fmaf(av[i], wv[j], acc[i][j]);
        }
        __syncthreads();
    }

    // epilogue: bias, store h1, per-column partial stats over valid rows
    int c0 = tc * 8;
    float bb[8];
#pragma unroll
    for (int j = 0; j < 8; ++j) bb[j] = b[c0 + j];

    float s[8], q[8];
#pragma unroll
    for (int j = 0; j < 8; ++j) { s[j] = 0.f; q[j] = 0.f; }

#pragma unroll
    for (int i = 0; i < 4; ++i) {
        int gr = r0 + tr * 4 + i;
        if (gr < NNODES) {
            float v[8];
#pragma unroll
            for (int j = 0; j < 8; ++j) {
                v[j] = acc[i][j] + bb[j];
                s[j] += v[j];
                q[j] += v[j] * v[j];
            }
            *(float4*)(h1 + (size_t)gr * 128 + c0) = make_float4(v[0], v[1], v[2], v[3]);
            *(float4*)(h1 + (size_t)gr * 128 + c0 + 4) = make_float4(v[4], v[5], v[6], v[7]);
        }
    }
#pragma unroll
    for (int j = 0; j < 8; ++j) {
        Sred[0][tr][c0 + j] = s[j];
        Sred[1][tr][c0 + j] = q[j];
    }
    __syncthreads();
    if (t < 128) {
        float ts = 0.f, tq = 0.f;
#pragma unroll
        for (int g = 0; g < 16; ++g) {
            ts += Sred[0][g][t];
            tq += Sred[1][g][t];
        }
        atomicAdd(stats + t, ts);
        atomicAdd(stats + 128 + t, tq);
    }
}

// ---------------- fused BN + ReLU + GEMM2 + ReLU + GEMM3 + ReLU + GEMM4 ----------------
__global__ __launch_bounds__(256) void k_mlp(const float* __restrict__ h1,
                                             const float* __restrict__ stats,
                                             const float* __restrict__ gamma,
                                             const float* __restrict__ beta,
                                             const float* __restrict__ W2,
                                             const float* __restrict__ b2,
                                             const float* __restrict__ Wm1,
                                             const float* __restrict__ bm1,
                                             const float* __restrict__ Wm2,
                                             const float* __restrict__ bm2,
                                             float* __restrict__ out) {
    __shared__ float cur[128][68];   // activation tile transposed [k][row], padded
    __shared__ float scale[128], shift[128];

    int t = threadIdx.x;
    int tc = t & 15;
    int tr = t >> 4;
    int r0 = blockIdx.x * 64;

    // recompute BN affine from raw stats (cheap, saves a kernel launch)
    if (t < 128) {
        float mean = stats[t] * (1.0f / NNODES);
        float var = stats[128 + t] * (1.0f / NNODES) - mean * mean;
        var = fmaxf(var, 0.0f);
        float inv = rsqrtf(var + 1e-5f);
        float sc = gamma[t] * inv;
        scale[t] = sc;
        shift[t] = beta[t] - mean * sc;
    }
    __syncthreads();

    // stage h1 tile with BN + ReLU applied, transposed
#pragma unroll
    for (int z = 0; z < 8; ++z) {
        int idx = t + z * 256;        // 0..2047
        int row = idx >> 5;           // 0..63
        int kq = (idx & 31) * 4;      // 0..124
        int gr = r0 + row;
        float4 v = make_float4(0.f, 0.f, 0.f, 0.f);
        if (gr < NNODES) {
            v = *(const float4*)(h1 + (size_t)gr * 128 + kq);
            v.x = fmaxf(v.x * scale[kq + 0] + shift[kq + 0], 0.f);
            v.y = fmaxf(v.y * scale[kq + 1] + shift[kq + 1], 0.f);
            v.z = fmaxf(v.z * scale[kq + 2] + shift[kq + 2], 0.f);
            v.w = fmaxf(v.w * scale[kq + 3] + shift[kq + 3], 0.f);
        }
        cur[kq + 0][row] = v.x;
        cur[kq + 1][row] = v.y;
        cur[kq + 2][row] = v.z;
        cur[kq + 3][row] = v.w;
    }
    __syncthreads();

    float acc[4][8];

    // ---- GEMM2: cur @ W2, +b2, ReLU ----
#pragma unroll
    for (int i = 0; i < 4; ++i)
#pragma unroll
        for (int j = 0; j < 8; ++j) acc[i][j] = 0.0f;
#pragma unroll 4
    for (int k = 0; k < 128; ++k) {
        float4 a = *(const float4*)&cur[k][tr * 4];
        float4 w0 = *(const float4*)(W2 + (size_t)k * 128 + tc * 8);
        float4 w1 = *(const float4*)(W2 + (size_t)k * 128 + tc * 8 + 4);
        float av[4] = {a.x, a.y, a.z, a.w};
        float wv[8] = {w0.x, w0.y, w0.z, w0.w, w1.x, w1.y, w1.z, w1.w};
#pragma unroll
        for (int i = 0; i < 4; ++i)
#pragma unroll
            for (int j = 0; j < 8; ++j) acc[i][j] = fmaf(av[i], wv[j], acc[i][j]);
    }
    __syncthreads();  // all reads of cur done
    {
        int c0 = tc * 8;
#pragma unroll
        for (int j = 0; j < 8; ++j) {
            float bj = b2[c0 + j];
            float4 vv;
            vv.x = fmaxf(acc[0][j] + bj, 0.f);
            vv.y = fmaxf(acc[1][j] + bj, 0.f);
            vv.z = fmaxf(acc[2][j] + bj, 0.f);
            vv.w = fmaxf(acc[3][j] + bj, 0.f);
            *(float4*)&cur[c0 + j][tr * 4] = vv;
        }
    }
    __syncthreads();

    // ---- GEMM3: cur @ Wm1, +bm1, ReLU ----
#pragma unroll
    for (int i = 0; i < 4; ++i)
#pragma unroll
        for (int j = 0; j < 8; ++j) acc[i][j] = 0.0f;
#pragma unroll 4
    for (int k = 0; k < 128; ++k) {
        float4 a = *(const float4*)&cur[k][tr * 4];
        float4 w0 = *(const float4*)(Wm1 + (size_t)k * 128 + tc * 8);
        float4 w1 = *(const float4*)(Wm1 + (size_t)k * 128 + tc * 8 + 4);
        float av[4] = {a.x, a.y, a.z, a.w};
        float wv[8] = {w0.x, w0.y, w0.z, w0.w, w1.x, w1.y, w1.z, w1.w};
#pragma unroll
        for (int i = 0; i < 4; ++i)
#pragma unroll
            for (int j = 0; j < 8; ++j) acc[i][j] = fmaf(av[i], wv[j], acc[i][j]);
    }
    __syncthreads();
    {
        int c0 = tc * 8;
#pragma unroll
        for (int j = 0; j < 8; ++j) {
            float bj = bm1[c0 + j];
            float4 vv;
            vv.x = fmaxf(acc[0][j] + bj, 0.f);
            vv.y = fmaxf(acc[1][j] + bj, 0.f);
            vv.z = fmaxf(acc[2][j] + bj, 0.f);
            vv.w = fmaxf(acc[3][j] + bj, 0.f);
            *(float4*)&cur[c0 + j][tr * 4] = vv;
        }
    }
    __syncthreads();

    // ---- GEMM4: cur @ Wm2 (128x64), +bm2, store ----
    float a2[4][4];
#pragma unroll
    for (int i = 0; i < 4; ++i)
#pragma unroll
        for (int j = 0; j < 4; ++j) a2[i][j] = 0.0f;
#pragma unroll 4
    for (int k = 0; k < 128; ++k) {
        float4 a = *(const float4*)&cur[k][tr * 4];
        float4 w = *(const float4*)(Wm2 + (size_t)k * 64 + tc * 4);
        float av[4] = {a.x, a.y, a.z, a.w};
        float wv[4] = {w.x, w.y, w.z, w.w};
#pragma unroll
        for (int i = 0; i < 4; ++i)
#pragma unroll
            for (int j = 0; j < 4; ++j) a2[i][j] = fmaf(av[i], wv[j], a2[i][j]);
    }
    {
        int c0 = tc * 4;
        float bb[4] = {bm2[c0], bm2[c0 + 1], bm2[c0 + 2], bm2[c0 + 3]};
#pragma unroll
        for (int i = 0; i < 4; ++i) {
            int gr = r0 + tr * 4 + i;
            if (gr < NNODES) {
                float4 vv = make_float4(a2[i][0] + bb[0], a2[i][1] + bb[1],
                                        a2[i][2] + bb[2], a2[i][3] + bb[3]);
                *(float4*)(out + (size_t)gr * 64 + c0) = vv;
            }
        }
    }
}

// ---------------- launch ----------------
extern "C" void kernel_launch(void* const* d_in, const int* in_sizes, int n_in,
                              void* d_out, int out_size, void* d_ws, size_t ws_size,
                              hipStream_t stream) {
    const float* x     = (const float*)d_in[0];
    const int*   ei    = (const int*)d_in[1];
    const float* W1    = (const float*)d_in[2];
    const float* b1    = (const float*)d_in[3];
    const float* gamma = (const float*)d_in[4];
    const float* beta  = (const float*)d_in[5];
    const float* W2    = (const float*)d_in[6];
    const float* b2    = (const float*)d_in[7];
    const float* Wm1   = (const float*)d_in[8];
    const float* bm1   = (const float*)d_in[9];
    const float* Wm2   = (const float*)d_in[10];
    const float* bm2   = (const float*)d_in[11];
    float* out = (float*)d_out;

    char* ws = (char*)d_ws;
    float* buf   = (float*)ws;                                   // N*128 f32 = 51.2 MB
    float* h1    = (float*)(ws + (size_t)NNODES * 128 * 4);      // N*128 f32 = 51.2 MB
    float* stats = (float*)(ws + (size_t)NNODES * 128 * 4 * 2);  // 256 f32

    k_zero_stats<<<1, 256, 0, stream>>>(stats);
    k_copy<<<(NNODES * 32 + 255) / 256, 256, 0, stream>>>((const float4*)x, (float4*)buf,
                                                          NNODES * 32);
    k_scatter<<<(NEDGES * 32) / 256, 256, 0, stream>>>(ei, (const float4*)x, buf);

    int nblk = (NNODES + 63) / 64;
    k_gemm1<<<nblk, 256, 0, stream>>>(buf, W1, b1, h1, stats);
    k_mlp<<<nblk, 256, 0, stream>>>(h1, stats, gamma, beta, W2, b2, Wm1, bm1, Wm2, bm2, out);
}

// Round 2
// 360.281 us; speedup vs baseline: 3.4695x; 3.4695x over previous
//
#include <hip/hip_runtime.h>
#include <hip/hip_bf16.h>
#include <stdint.h>

#define NNODES 100000
#define NEDGES 600000
#define SCAN_CHUNK 1024
#define SCAN_NB 98  // ceil(100000/1024)

// ---------------- CSR build ----------------

__global__ __launch_bounds__(256) void k_init(int* __restrict__ cnt, float* __restrict__ stats) {
    int i = blockIdx.x * 256 + threadIdx.x;
    if (i < NNODES) cnt[i] = 0;
    if (i < 256) stats[i] = 0.0f;
}

__global__ __launch_bounds__(256) void k_hist(const int* __restrict__ ei, int* __restrict__ cnt) {
    int e = blockIdx.x * 256 + threadIdx.x;
    if (e < NEDGES) atomicAdd(&cnt[ei[NEDGES + e]], 1);
}

// per-block sums of 1024 counts
__global__ __launch_bounds__(256) void k_scan1(const int* __restrict__ cnt, int* __restrict__ bsums) {
    __shared__ int sd[256];
    int b = blockIdx.x, t = threadIdx.x;
    int base = b * SCAN_CHUNK + t * 4;
    int s = 0;
#pragma unroll
    for (int i = 0; i < 4; ++i) {
        int idx = base + i;
        if (idx < NNODES) s += cnt[idx];
    }
    sd[t] = s;
    __syncthreads();
    for (int off = 128; off > 0; off >>= 1) {
        if (t < off) sd[t] += sd[t + off];
        __syncthreads();
    }
    if (t == 0) bsums[b] = sd[0];
}

// serial scan of 98 block sums (tiny)
__global__ __launch_bounds__(64) void k_scan2(int* __restrict__ bsums, int* __restrict__ rowptr) {
    if (threadIdx.x == 0 && blockIdx.x == 0) {
        int run = 0;
        for (int b = 0; b < SCAN_NB; ++b) {
            int v = bsums[b];
            bsums[b] = run;
            run += v;
        }
        rowptr[NNODES] = run;  // == NEDGES
    }
}

// full exclusive scan: rowptr[i] and pos[i] (fill cursor). cnt and pos may alias.
__global__ __launch_bounds__(256) void k_scan3(const int* __restrict__ cnt,
                                               const int* __restrict__ bsums,
                                               int* __restrict__ rowptr, int* __restrict__ pos) {
    __shared__ int sd[256];
    int b = blockIdx.x, t = threadIdx.x;
    int base = b * SCAN_CHUNK + t * 4;
    int v[4];
    int s = 0;
#pragma unroll
    for (int i = 0; i < 4; ++i) {
        int idx = base + i;
        v[i] = (idx < NNODES) ? cnt[idx] : 0;
        s += v[i];
    }
    sd[t] = s;
    __syncthreads();
    // Hillis-Steele inclusive scan over thread partials
    for (int off = 1; off < 256; off <<= 1) {
        int val = (t >= off) ? sd[t - off] : 0;
        __syncthreads();
        sd[t] += val;
        __syncthreads();
    }
    int run = sd[t] - s + bsums[b];  // exclusive prefix for this thread's chunk
#pragma unroll
    for (int i = 0; i < 4; ++i) {
        int idx = base + i;
        if (idx < NNODES) {
            rowptr[idx] = run;
            pos[idx] = run;
            run += v[i];
        }
    }
}

__global__ __launch_bounds__(256) void k_fill(const int* __restrict__ ei, int* __restrict__ pos,
                                              int* __restrict__ elist) {
    int e = blockIdx.x * 256 + threadIdx.x;
    if (e >= NEDGES) return;
    int src = ei[e];
    int dst = ei[NEDGES + e];
    int p = atomicAdd(&pos[dst], 1);
    elist[p] = src;
}

// ---------------- gather-aggregate: buf[i] = x[i] + sum_{j in N(i)} x[j] ----------------
// one wave (64 lanes) per node; each lane owns 2 contiguous floats (float2)
__global__ __launch_bounds__(256) void k_agg(const float* __restrict__ x,
                                             const int* __restrict__ rowptr,
                                             const int* __restrict__ elist,
                                             float* __restrict__ buf) {
    int t = threadIdx.x;
    int w = t >> 6, lane = t & 63;
    int node = blockIdx.x * 4 + w;
    if (node >= NNODES) return;
    int beg = rowptr[node], end = rowptr[node + 1];
    float2 acc = *(const float2*)(x + (size_t)node * 128 + lane * 2);
    for (int p = beg; p < end; ++p) {
        int s = elist[p];
        float2 v = *(const float2*)(x + (size_t)s * 128 + lane * 2);
        acc.x += v.x;
        acc.y += v.y;
    }
    *(float2*)(buf + (size_t)node * 128 + lane * 2) = acc;
}

// ---------------- GEMM1 + BN stats ----------------
__global__ __launch_bounds__(256) void k_gemm1(const float* __restrict__ A,
                                               const float* __restrict__ W,
                                               const float* __restrict__ b,
                                               float* __restrict__ h1,
                                               float* __restrict__ stats) {
    __shared__ float As[32][68];
    __shared__ float Ws[32][128];
    __shared__ float Sred[2][16][128];

    int t = threadIdx.x;
    int tc = t & 15;
    int tr = t >> 4;
    int r0 = blockIdx.x * 64;

    float acc[4][8];
#pragma unroll
    for (int i = 0; i < 4; ++i)
#pragma unroll
        for (int j = 0; j < 8; ++j) acc[i][j] = 0.0f;

    for (int kc = 0; kc < 128; kc += 32) {
#pragma unroll
        for (int z = 0; z < 2; ++z) {
            int idx = t + z * 256;
            int row = idx >> 3;
            int k4 = (idx & 7) * 4;
            int gr = r0 + row;
            float4 v = make_float4(0.f, 0.f, 0.f, 0.f);
            if (gr < NNODES) v = *(const float4*)(A + (size_t)gr * 128 + kc + k4);
            As[k4 + 0][row] = v.x;
            As[k4 + 1][row] = v.y;
            As[k4 + 2][row] = v.z;
            As[k4 + 3][row] = v.w;
        }
#pragma unroll
        for (int z = 0; z < 4; ++z) {
            int idx = t + z * 256;
            int k = idx >> 5;
            int c4 = (idx & 31) * 4;
            *(float4*)&Ws[k][c4] = *(const float4*)(W + (size_t)(kc + k) * 128 + c4);
        }
        __syncthreads();
#pragma unroll 4
        for (int k = 0; k < 32; ++k) {
            float4 a = *(const float4*)&As[k][tr * 4];
            float4 w0 = *(const float4*)&Ws[k][tc * 8];
            float4 w1 = *(const float4*)&Ws[k][tc * 8 + 4];
            float av[4] = {a.x, a.y, a.z, a.w};
            float wv[8] = {w0.x, w0.y, w0.z, w0.w, w1.x, w1.y, w1.z, w1.w};
#pragma unroll
            for (int i = 0; i < 4; ++i)
#pragma unroll
                for (int j = 0; j < 8; ++j) acc[i][j] = fmaf(av[i], wv[j], acc[i][j]);
        }
        __syncthreads();
    }

    int c0 = tc * 8;
    float bb[8];
#pragma unroll
    for (int j = 0; j < 8; ++j) bb[j] = b[c0 + j];

    float s[8], q[8];
#pragma unroll
    for (int j = 0; j < 8; ++j) { s[j] = 0.f; q[j] = 0.f; }

#pragma unroll
    for (int i = 0; i < 4; ++i) {
        int gr = r0 + tr * 4 + i;
        if (gr < NNODES) {
            float v[8];
#pragma unroll
            for (int j = 0; j < 8; ++j) {
                v[j] = acc[i][j] + bb[j];
                s[j] += v[j];
                q[j] += v[j] * v[j];
            }
            *(float4*)(h1 + (size_t)gr * 128 + c0) = make_float4(v[0], v[1], v[2], v[3]);
            *(float4*)(h1 + (size_t)gr * 128 + c0 + 4) = make_float4(v[4], v[5], v[6], v[7]);
        }
    }
#pragma unroll
    for (int j = 0; j < 8; ++j) {
        Sred[0][tr][c0 + j] = s[j];
        Sred[1][tr][c0 + j] = q[j];
    }
    __syncthreads();
    if (t < 128) {
        float ts = 0.f, tq = 0.f;
#pragma unroll
        for (int g = 0; g < 16; ++g) {
            ts += Sred[0][g][t];
            tq += Sred[1][g][t];
        }
        atomicAdd(stats + t, ts);
        atomicAdd(stats + 128 + t, tq);
    }
}

// ---------------- fused BN + ReLU + GEMM2 + ReLU + GEMM3 + ReLU + GEMM4 ----------------
__global__ __launch_bounds__(256) void k_mlp(const float* __restrict__ h1,
                                             const float* __restrict__ stats,
                                             const float* __restrict__ gamma,
                                             const float* __restrict__ beta,
                                             const float* __restrict__ W2,
                                             const float* __restrict__ b2,
                                             const float* __restrict__ Wm1,
                                             const float* __restrict__ bm1,
                                             const float* __restrict__ Wm2,
                                             const float* __restrict__ bm2,
                                             float* __restrict__ out) {
    __shared__ float cur[128][68];
    __shared__ float scale[128], shift[128];

    int t = threadIdx.x;
    int tc = t & 15;
    int tr = t >> 4;
    int r0 = blockIdx.x * 64;

    if (t < 128) {
        float mean = stats[t] * (1.0f / NNODES);
        float var = stats[128 + t] * (1.0f / NNODES) - mean * mean;
        var = fmaxf(var, 0.0f);
        float inv = rsqrtf(var + 1e-5f);
        float sc = gamma[t] * inv;
        scale[t] = sc;
        shift[t] = beta[t] - mean * sc;
    }
    __syncthreads();

#pragma unroll
    for (int z = 0; z < 8; ++z) {
        int idx = t + z * 256;
        int row = idx >> 5;
        int kq = (idx & 31) * 4;
        int gr = r0 + row;
        float4 v = make_float4(0.f, 0.f, 0.f, 0.f);
        if (gr < NNODES) {
            v = *(const float4*)(h1 + (size_t)gr * 128 + kq);
            v.x = fmaxf(v.x * scale[kq + 0] + shift[kq + 0], 0.f);
            v.y = fmaxf(v.y * scale[kq + 1] + shift[kq + 1], 0.f);
            v.z = fmaxf(v.z * scale[kq + 2] + shift[kq + 2], 0.f);
            v.w = fmaxf(v.w * scale[kq + 3] + shift[kq + 3], 0.f);
        }
        cur[kq + 0][row] = v.x;
        cur[kq + 1][row] = v.y;
        cur[kq + 2][row] = v.z;
        cur[kq + 3][row] = v.w;
    }
    __syncthreads();

    float acc[4][8];

#pragma unroll
    for (int i = 0; i < 4; ++i)
#pragma unroll
        for (int j = 0; j < 8; ++j) acc[i][j] = 0.0f;
#pragma unroll 4
    for (int k = 0; k < 128; ++k) {
        float4 a = *(const float4*)&cur[k][tr * 4];
        float4 w0 = *(const float4*)(W2 + (size_t)k * 128 + tc * 8);
        float4 w1 = *(const float4*)(W2 + (size_t)k * 128 + tc * 8 + 4);
        float av[4] = {a.x, a.y, a.z, a.w};
        float wv[8] = {w0.x, w0.y, w0.z, w0.w, w1.x, w1.y, w1.z, w1.w};
#pragma unroll
        for (int i = 0; i < 4; ++i)
#pragma unroll
            for (int j = 0; j < 8; ++j) acc[i][j] = fmaf(av[i], wv[j], acc[i][j]);
    }
    __syncthreads();
    {
        int c0 = tc * 8;
#pragma unroll
        for (int j = 0; j < 8; ++j) {
            float bj = b2[c0 + j];
            float4 vv;
            vv.x = fmaxf(acc[0][j] + bj, 0.f);
            vv.y = fmaxf(acc[1][j] + bj, 0.f);
            vv.z = fmaxf(acc[2][j] + bj, 0.f);
            vv.w = fmaxf(acc[3][j] + bj, 0.f);
            *(float4*)&cur[c0 + j][tr * 4] = vv;
        }
    }
    __syncthreads();

#pragma unroll
    for (int i = 0; i < 4; ++i)
#pragma unroll
        for (int j = 0; j < 8; ++j) acc[i][j] = 0.0f;
#pragma unroll 4
    for (int k = 0; k < 128; ++k) {
        float4 a = *(const float4*)&cur[k][tr * 4];
        float4 w0 = *(const float4*)(Wm1 + (size_t)k * 128 + tc * 8);
        float4 w1 = *(const float4*)(Wm1 + (size_t)k * 128 + tc * 8 + 4);
        float av[4] = {a.x, a.y, a.z, a.w};
        float wv[8] = {w0.x, w0.y, w0.z, w0.w, w1.x, w1.y, w1.z, w1.w};
#pragma unroll
        for (int i = 0; i < 4; ++i)
#pragma unroll
            for (int j = 0; j < 8; ++j) acc[i][j] = fmaf(av[i], wv[j], acc[i][j]);
    }
    __syncthreads();
    {
        int c0 = tc * 8;
#pragma unroll
        for (int j = 0; j < 8; ++j) {
            float bj = bm1[c0 + j];
            float4 vv;
            vv.x = fmaxf(acc[0][j] + bj, 0.f);
            vv.y = fmaxf(acc[1][j] + bj, 0.f);
            vv.z = fmaxf(acc[2][j] + bj, 0.f);
            vv.w = fmaxf(acc[3][j] + bj, 0.f);
            *(float4*)&cur[c0 + j][tr * 4] = vv;
        }
    }
    __syncthreads();

    float a2[4][4];
#pragma unroll
    for (int i = 0; i < 4; ++i)
#pragma unroll
        for (int j = 0; j < 4; ++j) a2[i][j] = 0.0f;
#pragma unroll 4
    for (int k = 0; k < 128; ++k) {
        float4 a = *(const float4*)&cur[k][tr * 4];
        float4 w = *(const float4*)(Wm2 + (size_t)k * 64 + tc * 4);
        float av[4] = {a.x, a.y, a.z, a.w};
        float wv[4] = {w.x, w.y, w.z, w.w};
#pragma unroll
        for (int i = 0; i < 4; ++i)
#pragma unroll
            for (int j = 0; j < 4; ++j) a2[i][j] = fmaf(av[i], wv[j], a2[i][j]);
    }
    {
        int c0 = tc * 4;
        float bb[4] = {bm2[c0], bm2[c0 + 1], bm2[c0 + 2], bm2[c0 + 3]};
#pragma unroll
        for (int i = 0; i < 4; ++i) {
            int gr = r0 + tr * 4 + i;
            if (gr < NNODES) {
                float4 vv = make_float4(a2[i][0] + bb[0], a2[i][1] + bb[1],
                                        a2[i][2] + bb[2], a2[i][3] + bb[3]);
                *(float4*)(out + (size_t)gr * 64 + c0) = vv;
            }
        }
    }
}

// ---------------- launch ----------------
extern "C" void kernel_launch(void* const* d_in, const int* in_sizes, int n_in,
                              void* d_out, int out_size, void* d_ws, size_t ws_size,
                              hipStream_t stream) {
    const float* x     = (const float*)d_in[0];
    const int*   ei    = (const int*)d_in[1];
    const float* W1    = (const float*)d_in[2];
    const float* b1    = (const float*)d_in[3];
    const float* gamma = (const float*)d_in[4];
    const float* beta  = (const float*)d_in[5];
    const float* W2    = (const float*)d_in[6];
    const float* b2    = (const float*)d_in[7];
    const float* Wm1   = (const float*)d_in[8];
    const float* bm1   = (const float*)d_in[9];
    const float* Wm2   = (const float*)d_in[10];
    const float* bm2   = (const float*)d_in[11];
    float* out = (float*)d_out;

    char* ws = (char*)d_ws;
    float* buf    = (float*)ws;                                  // N*128 f32
    float* h1     = buf + (size_t)NNODES * 128;                  // N*128 f32
    float* stats  = h1 + (size_t)NNODES * 128;                   // 256 f32
    int*   rowptr = (int*)(stats + 256);                         // N+1
    int*   pos    = rowptr + (NNODES + 1);                       // N (counts, then fill cursor)
    int*   elist  = pos + NNODES;                                // E
    int*   bsums  = elist + NEDGES;                              // 128

    int gE = (NEDGES + 255) / 256;
    int gN = (NNODES + 255) / 256;

    k_init<<<gN, 256, 0, stream>>>(pos, stats);
    k_hist<<<gE, 256, 0, stream>>>(ei, pos);
    k_scan1<<<SCAN_NB, 256, 0, stream>>>(pos, bsums);
    k_scan2<<<1, 64, 0, stream>>>(bsums, rowptr);
    k_scan3<<<SCAN_NB, 256, 0, stream>>>(pos, bsums, rowptr, pos);
    k_fill<<<gE, 256, 0, stream>>>(ei, pos, elist);
    k_agg<<<(NNODES + 3) / 4, 256, 0, stream>>>(x, rowptr, elist, buf);

    int nblk = (NNODES + 63) / 64;
    k_gemm1<<<nblk, 256, 0, stream>>>(buf, W1, b1, h1, stats);
    k_mlp<<<nblk, 256, 0, stream>>>(h1, stats, gamma, beta, W2, b2, Wm1, bm1, Wm2, bm2, out);
}

// Round 3
// 235.255 us; speedup vs baseline: 5.3133x; 1.5314x over previous
//
#include <hip/hip_runtime.h>
#include <hip/hip_bf16.h>
#include <stdint.h>

#define NNODES 100000
#define NEDGES 600000
#define SCAN_CHUNK 1024
#define SCAN_NB 98  // ceil(100000/1024)

typedef __attribute__((ext_vector_type(8))) short bf16x8;
typedef __attribute__((ext_vector_type(4))) float f32x4;

__device__ inline float b2f(short b) {
    union { unsigned u; float f; } v;
    v.u = ((unsigned)(unsigned short)b) << 16;
    return v.f;
}
__device__ inline short f2b(float f) {
    union { float f; unsigned u; } v;
    v.f = f;
    unsigned r = (v.u + 0x7FFFu + ((v.u >> 16) & 1u)) >> 16;
    return (short)r;
}
// LDS XOR swizzle: bank-conflict-free ds_read_b128 of row-major [row][128*2B] bf16 tiles
__device__ inline int swz(int row, int kbyte) {
    return (row * 256 + kbyte) ^ ((row & 7) << 4);
}
#define MFMA16(a, b, c) __builtin_amdgcn_mfma_f32_16x16x32_bf16(a, b, c, 0, 0, 0)

// ---------------- CSR build ----------------

__global__ __launch_bounds__(256) void k_init(int* __restrict__ cnt, float* __restrict__ stats) {
    int i = blockIdx.x * 256 + threadIdx.x;
    if (i < NNODES) cnt[i] = 0;
    if (i < 256) stats[i] = 0.0f;
}

__global__ __launch_bounds__(256) void k_hist(const int* __restrict__ ei, int* __restrict__ cnt) {
    int e = blockIdx.x * 256 + threadIdx.x;
    if (e < NEDGES) atomicAdd(&cnt[ei[NEDGES + e]], 1);
}

__global__ __launch_bounds__(256) void k_scan1(const int* __restrict__ cnt, int* __restrict__ bsums) {
    __shared__ int sd[256];
    int b = blockIdx.x, t = threadIdx.x;
    int base = b * SCAN_CHUNK + t * 4;
    int s = 0;
#pragma unroll
    for (int i = 0; i < 4; ++i) {
        int idx = base + i;
        if (idx < NNODES) s += cnt[idx];
    }
    sd[t] = s;
    __syncthreads();
    for (int off = 128; off > 0; off >>= 1) {
        if (t < off) sd[t] += sd[t + off];
        __syncthreads();
    }
    if (t == 0) bsums[b] = sd[0];
}

__global__ __launch_bounds__(64) void k_scan2(int* __restrict__ bsums, int* __restrict__ rowptr) {
    if (threadIdx.x == 0 && blockIdx.x == 0) {
        int run = 0;
        for (int b = 0; b < SCAN_NB; ++b) {
            int v = bsums[b];
            bsums[b] = run;
            run += v;
        }
        rowptr[NNODES] = run;
    }
}

__global__ __launch_bounds__(256) void k_scan3(const int* __restrict__ cnt,
                                               const int* __restrict__ bsums,
                                               int* __restrict__ rowptr, int* __restrict__ pos) {
    __shared__ int sd[256];
    int b = blockIdx.x, t = threadIdx.x;
    int base = b * SCAN_CHUNK + t * 4;
    int v[4];
    int s = 0;
#pragma unroll
    for (int i = 0; i < 4; ++i) {
        int idx = base + i;
        v[i] = (idx < NNODES) ? cnt[idx] : 0;
        s += v[i];
    }
    sd[t] = s;
    __syncthreads();
    for (int off = 1; off < 256; off <<= 1) {
        int val = (t >= off) ? sd[t - off] : 0;
        __syncthreads();
        sd[t] += val;
        __syncthreads();
    }
    int run = sd[t] - s + bsums[b];
#pragma unroll
    for (int i = 0; i < 4; ++i) {
        int idx = base + i;
        if (idx < NNODES) {
            rowptr[idx] = run;
            pos[idx] = run;
            run += v[i];
        }
    }
}

__global__ __launch_bounds__(256) void k_fill(const int* __restrict__ ei, int* __restrict__ pos,
                                              int* __restrict__ elist) {
    int e = blockIdx.x * 256 + threadIdx.x;
    if (e >= NEDGES) return;
    int src = ei[e];
    int dst = ei[NEDGES + e];
    int p = atomicAdd(&pos[dst], 1);
    elist[p] = src;
}

// ---------------- conversions ----------------

__global__ __launch_bounds__(256) void k_xb(const float* __restrict__ x, short* __restrict__ xb,
                                            int n8) {
    int i = blockIdx.x * 256 + threadIdx.x;
    if (i >= n8) return;
    const float4* p = (const float4*)(x + (size_t)i * 8);
    float4 a = p[0], b = p[1];
    bf16x8 o;
    o[0] = f2b(a.x); o[1] = f2b(a.y); o[2] = f2b(a.z); o[3] = f2b(a.w);
    o[4] = f2b(b.x); o[5] = f2b(b.y); o[6] = f2b(b.z); o[7] = f2b(b.w);
    *(bf16x8*)(xb + (size_t)i * 8) = o;
}

// weights -> bf16, transposed to [out_col][k] so B fragments are contiguous
__global__ __launch_bounds__(256) void k_wconv(const float* __restrict__ W1,
                                               const float* __restrict__ W2,
                                               const float* __restrict__ Wm1,
                                               const float* __restrict__ Wm2,
                                               short* __restrict__ Wt) {
    int i = blockIdx.x * 256 + threadIdx.x;  // 0..57343
    if (i >= 57344) return;
    float v;
    if (i < 16384) {
        int c = i >> 7, k = i & 127;
        v = W1[k * 128 + c];
    } else if (i < 32768) {
        int j = i - 16384;
        int c = j >> 7, k = j & 127;
        v = W2[k * 128 + c];
    } else if (i < 49152) {
        int j = i - 32768;
        int c = j >> 7, k = j & 127;
        v = Wm1[k * 128 + c];
    } else {
        int j = i - 49152;
        int c = j >> 7, k = j & 127;
        v = Wm2[k * 64 + c];
    }
    Wt[i] = f2b(v);
}

// ---------------- gather-aggregate (bf16 in, fp32 accum, bf16 out) ----------------
__global__ __launch_bounds__(256) void k_agg(const short* __restrict__ xb,
                                             const int* __restrict__ rowptr,
                                             const int* __restrict__ elist,
                                             short* __restrict__ bufb) {
    int t = threadIdx.x;
    int w = t >> 6, lane = t & 63;
    int node = blockIdx.x * 4 + w;
    if (node >= NNODES) return;
    int beg = rowptr[node], end = rowptr[node + 1];
    const uint32_t* xr = (const uint32_t*)xb;
    uint32_t sv = xr[(size_t)node * 64 + lane];
    float ax = b2f((short)(sv & 0xFFFF)), ay = b2f((short)(sv >> 16));
    for (int p = beg; p < end; ++p) {
        int s = elist[p];
        uint32_t v = xr[(size_t)s * 64 + lane];
        ax += b2f((short)(v & 0xFFFF));
        ay += b2f((short)(v >> 16));
    }
    uint32_t o = ((uint32_t)(unsigned short)f2b(ay) << 16) | (uint32_t)(unsigned short)f2b(ax);
    ((uint32_t*)bufb)[(size_t)node * 64 + lane] = o;
}

// ---------------- GEMM1 (MFMA) + BN stats ----------------
__global__ __launch_bounds__(256) void k_gemm1(const short* __restrict__ Ab,
                                               const short* __restrict__ W1t,
                                               const float* __restrict__ b1,
                                               short* __restrict__ h1b,
                                               float* __restrict__ stats) {
    __shared__ __align__(16) short act[128 * 128];
    __shared__ __align__(16) short wt[128 * 128];
    __shared__ float Sred[2][4][128];

    int t = threadIdx.x;
    int w = t >> 6, l = t & 63;
    int r0 = blockIdx.x * 128;

#pragma unroll
    for (int z = 0; z < 8; ++z) {
        int idx = t + z * 256;
        int row = idx >> 4, kc = idx & 15;
        int gr = r0 + row;
        bf16x8 v = (bf16x8){0, 0, 0, 0, 0, 0, 0, 0};
        if (gr < NNODES) v = *(const bf16x8*)(Ab + (size_t)gr * 128 + kc * 8);
        *(bf16x8*)((char*)act + swz(row, kc * 16)) = v;
    }
#pragma unroll
    for (int z = 0; z < 8; ++z) {
        int idx = t + z * 256;
        int row = idx >> 4, kc = idx & 15;
        *(bf16x8*)((char*)wt + swz(row, kc * 16)) =
            *(const bf16x8*)(W1t + (size_t)row * 128 + kc * 8);
    }
    __syncthreads();

    int row0 = (w & 1) * 64, col0 = (w >> 1) * 64;
    f32x4 acc[4][4];
#pragma unroll
    for (int r = 0; r < 4; ++r)
#pragma unroll
        for (int c = 0; c < 4; ++c) acc[r][c] = (f32x4){0.f, 0.f, 0.f, 0.f};

#pragma unroll
    for (int kb = 0; kb < 4; ++kb) {
        int kbyte = kb * 64 + (l >> 4) * 16;
        bf16x8 af[4], bw[4];
#pragma unroll
        for (int r = 0; r < 4; ++r)
            af[r] = *(const bf16x8*)((char*)act + swz(row0 + r * 16 + (l & 15), kbyte));
#pragma unroll
        for (int c = 0; c < 4; ++c)
            bw[c] = *(const bf16x8*)((char*)wt + swz(col0 + c * 16 + (l & 15), kbyte));
#pragma unroll
        for (int r = 0; r < 4; ++r)
#pragma unroll
            for (int c = 0; c < 4; ++c) acc[r][c] = MFMA16(af[r], bw[c], acc[r][c]);
    }

    // bias + per-column stats partials (fp32, pre-rounding)
    float s[4], q[4];
#pragma unroll
    for (int c = 0; c < 4; ++c) { s[c] = 0.f; q[c] = 0.f; }
#pragma unroll
    for (int c = 0; c < 4; ++c) {
        float bias = b1[col0 + c * 16 + (l & 15)];
#pragma unroll
        for (int r = 0; r < 4; ++r)
#pragma unroll
            for (int rr = 0; rr < 4; ++rr) {
                float v = acc[r][c][rr] + bias;
                acc[r][c][rr] = v;
                int grow = r0 + row0 + r * 16 + (l >> 4) * 4 + rr;
                if (grow < NNODES) { s[c] += v; q[c] += v * v; }
            }
    }
#pragma unroll
    for (int c = 0; c < 4; ++c) {
        s[c] += __shfl_xor(s[c], 16); s[c] += __shfl_xor(s[c], 32);
        q[c] += __shfl_xor(q[c], 16); q[c] += __shfl_xor(q[c], 32);
    }
    if (l < 16) {
#pragma unroll
        for (int c = 0; c < 4; ++c) {
            Sred[0][w][col0 + c * 16 + l] = s[c];
            Sred[1][w][col0 + c * 16 + l] = q[c];
        }
    }
    __syncthreads();
    if (t < 128) {
        int wb = (t < 64) ? 0 : 2;
        atomicAdd(stats + t, Sred[0][wb][t] + Sred[0][wb + 1][t]);
        atomicAdd(stats + 128 + t, Sred[1][wb][t] + Sred[1][wb + 1][t]);
    }

    // redistribute C (bf16) into act, then coalesced copy to global
#pragma unroll
    for (int r = 0; r < 4; ++r)
#pragma unroll
        for (int c = 0; c < 4; ++c)
#pragma unroll
            for (int rr = 0; rr < 4; ++rr) {
                int row = row0 + r * 16 + (l >> 4) * 4 + rr;
                int col = col0 + c * 16 + (l & 15);
                *(short*)((char*)act + swz(row, col * 2)) = f2b(acc[r][c][rr]);
            }
    __syncthreads();
#pragma unroll
    for (int z = 0; z < 8; ++z) {
        int idx = t + z * 256;
        int row = idx >> 4, kc = idx & 15;
        int gr = r0 + row;
        if (gr < NNODES)
            *(bf16x8*)(h1b + (size_t)gr * 128 + kc * 8) =
                *(const bf16x8*)((char*)act + swz(row, kc * 16));
    }
}

// ---------------- fused BN + ReLU + GEMM2 + ReLU + GEMM3 + ReLU + GEMM4 (MFMA) -------
__global__ __launch_bounds__(256) void k_mlp(const short* __restrict__ h1b,
                                             const float* __restrict__ stats,
                                             const float* __restrict__ gamma,
                                             const float* __restrict__ beta,
                                             const short* __restrict__ W2t,
                                             const float* __restrict__ b2,
                                             const short* __restrict__ Wm1t,
                                             const float* __restrict__ bm1,
                                             const short* __restrict__ Wm2t,
                                             const float* __restrict__ bm2,
                                             float* __restrict__ out) {
    __shared__ __align__(16) short act[128 * 128];
    __shared__ __align__(16) short wt[128 * 128];
    __shared__ float scale[128], shift[128];

    int t = threadIdx.x, w = t >> 6, l = t & 63;
    int r0 = blockIdx.x * 128;

    if (t < 128) {
        float mean = stats[t] * (1.0f / NNODES);
        float var = stats[128 + t] * (1.0f / NNODES) - mean * mean;
        var = fmaxf(var, 0.0f);
        float inv = rsqrtf(var + 1e-5f);
        float sc = gamma[t] * inv;
        scale[t] = sc;
        shift[t] = beta[t] - mean * sc;
    }
#pragma unroll
    for (int z = 0; z < 8; ++z) {
        int idx = t + z * 256;
        int row = idx >> 4, kc = idx & 15;
        *(bf16x8*)((char*)wt + swz(row, kc * 16)) =
            *(const bf16x8*)(W2t + (size_t)row * 128 + kc * 8);
    }
    __syncthreads();

    // stage h1 tile with BN + ReLU, bf16, swizzled
#pragma unroll
    for (int z = 0; z < 8; ++z) {
        int idx = t + z * 256;
        int row = idx >> 4, kc = idx & 15;
        int gr = r0 + row;
        bf16x8 o = (bf16x8){0, 0, 0, 0, 0, 0, 0, 0};
        if (gr < NNODES) {
            bf16x8 v = *(const bf16x8*)(h1b + (size_t)gr * 128 + kc * 8);
#pragma unroll
            for (int j = 0; j < 8; ++j) {
                int k = kc * 8 + j;
                float f = b2f(v[j]) * scale[k] + shift[k];
                o[j] = f2b(fmaxf(f, 0.f));
            }
        }
        *(bf16x8*)((char*)act + swz(row, kc * 16)) = o;
    }
    __syncthreads();

    int row0 = (w & 1) * 64, col0 = (w >> 1) * 64;
    f32x4 acc[4][4];

    // ---- GEMM2 ----
#pragma unroll
    for (int r = 0; r < 4; ++r)
#pragma unroll
        for (int c = 0; c < 4; ++c) acc[r][c] = (f32x4){0.f, 0.f, 0.f, 0.f};
#pragma unroll
    for (int kb = 0; kb < 4; ++kb) {
        int kbyte = kb * 64 + (l >> 4) * 16;
        bf16x8 af[4], bw[4];
#pragma unroll
        for (int r = 0; r < 4; ++r)
            af[r] = *(const bf16x8*)((char*)act + swz(row0 + r * 16 + (l & 15), kbyte));
#pragma unroll
        for (int c = 0; c < 4; ++c)
            bw[c] = *(const bf16x8*)((char*)wt + swz(col0 + c * 16 + (l & 15), kbyte));
#pragma unroll
        for (int r = 0; r < 4; ++r)
#pragma unroll
            for (int c = 0; c < 4; ++c) acc[r][c] = MFMA16(af[r], bw[c], acc[r][c]);
    }
    __syncthreads();
    // writeback relu(acc+b2) -> act; stage Wm1t -> wt
#pragma unroll
    for (int c = 0; c < 4; ++c) {
        float bias = b2[col0 + c * 16 + (l & 15)];
#pragma unroll
        for (int r = 0; r < 4; ++r)
#pragma unroll
            for (int rr = 0; rr < 4; ++rr) {
                int row = row0 + r * 16 + (l >> 4) * 4 + rr;
                int col = col0 + c * 16 + (l & 15);
                *(short*)((char*)act + swz(row, col * 2)) = f2b(fmaxf(acc[r][c][rr] + bias, 0.f));
            }
    }
#pragma unroll
    for (int z = 0; z < 8; ++z) {
        int idx = t + z * 256;
        int row = idx >> 4, kc = idx & 15;
        *(bf16x8*)((char*)wt + swz(row, kc * 16)) =
            *(const bf16x8*)(Wm1t + (size_t)row * 128 + kc * 8);
    }
    __syncthreads();

    // ---- GEMM3 ----
#pragma unroll
    for (int r = 0; r < 4; ++r)
#pragma unroll
        for (int c = 0; c < 4; ++c) acc[r][c] = (f32x4){0.f, 0.f, 0.f, 0.f};
#pragma unroll
    for (int kb = 0; kb < 4; ++kb) {
        int kbyte = kb * 64 + (l >> 4) * 16;
        bf16x8 af[4], bw[4];
#pragma unroll
        for (int r = 0; r < 4; ++r)
            af[r] = *(const bf16x8*)((char*)act + swz(row0 + r * 16 + (l & 15), kbyte));
#pragma unroll
        for (int c = 0; c < 4; ++c)
            bw[c] = *(const bf16x8*)((char*)wt + swz(col0 + c * 16 + (l & 15), kbyte));
#pragma unroll
        for (int r = 0; r < 4; ++r)
#pragma unroll
            for (int c = 0; c < 4; ++c) acc[r][c] = MFMA16(af[r], bw[c], acc[r][c]);
    }
    __syncthreads();
    // writeback relu(acc+bm1) -> act; stage Wm2t (64x128 = 16KB) -> wt
#pragma unroll
    for (int c = 0; c < 4; ++c) {
        float bias = bm1[col0 + c * 16 + (l & 15)];
#pragma unroll
        for (int r = 0; r < 4; ++r)
#pragma unroll
            for (int rr = 0; rr < 4; ++rr) {
                int row = row0 + r * 16 + (l >> 4) * 4 + rr;
                int col = col0 + c * 16 + (l & 15);
                *(short*)((char*)act + swz(row, col * 2)) = f2b(fmaxf(acc[r][c][rr] + bias, 0.f));
            }
    }
#pragma unroll
    for (int z = 0; z < 4; ++z) {
        int idx = t + z * 256;
        int row = idx >> 4, kc = idx & 15;
        *(bf16x8*)((char*)wt + swz(row, kc * 16)) =
            *(const bf16x8*)(Wm2t + (size_t)row * 128 + kc * 8);
    }
    __syncthreads();

    // ---- GEMM4: [128 x 64] ----
    int row0q = w * 32;
    f32x4 a2[2][4];
#pragma unroll
    for (int r = 0; r < 2; ++r)
#pragma unroll
        for (int c = 0; c < 4; ++c) a2[r][c] = (f32x4){0.f, 0.f, 0.f, 0.f};
#pragma unroll
    for (int kb = 0; kb < 4; ++kb) {
        int kbyte = kb * 64 + (l >> 4) * 16;
        bf16x8 af[2], bw[4];
#pragma unroll
        for (int r = 0; r < 2; ++r)
            af[r] = *(const bf16x8*)((char*)act + swz(row0q + r * 16 + (l & 15), kbyte));
#pragma unroll
        for (int c = 0; c < 4; ++c)
            bw[c] = *(const bf16x8*)((char*)wt + swz(c * 16 + (l & 15), kbyte));
#pragma unroll
        for (int r = 0; r < 2; ++r)
#pragma unroll
            for (int c = 0; c < 4; ++c) a2[r][c] = MFMA16(af[r], bw[c], a2[r][c]);
    }
#pragma unroll
    for (int c = 0; c < 4; ++c) {
        float bias = bm2[c * 16 + (l & 15)];
#pragma unroll
        for (int r = 0; r < 2; ++r)
#pragma unroll
            for (int rr = 0; rr < 4; ++rr) {
                int grow = r0 + row0q + r * 16 + (l >> 4) * 4 + rr;
                if (grow < NNODES)
                    out[(size_t)grow * 64 + c * 16 + (l & 15)] = a2[r][c][rr] + bias;
            }
    }
}

// ---------------- launch ----------------
extern "C" void kernel_launch(void* const* d_in, const int* in_sizes, int n_in,
                              void* d_out, int out_size, void* d_ws, size_t ws_size,
                              hipStream_t stream) {
    const float* x     = (const float*)d_in[0];
    const int*   ei    = (const int*)d_in[1];
    const float* W1    = (const float*)d_in[2];
    const float* b1    = (const float*)d_in[3];
    const float* gamma = (const float*)d_in[4];
    const float* beta  = (const float*)d_in[5];
    const float* W2    = (const float*)d_in[6];
    const float* b2    = (const float*)d_in[7];
    const float* Wm1   = (const float*)d_in[8];
    const float* bm1   = (const float*)d_in[9];
    const float* Wm2   = (const float*)d_in[10];
    const float* bm2   = (const float*)d_in[11];
    float* out = (float*)d_out;

    char* ws = (char*)d_ws;
    short* xb    = (short*)ws;                       // N*128 bf16
    short* bufb  = xb + (size_t)NNODES * 128;        // N*128 bf16
    short* h1b   = bufb + (size_t)NNODES * 128;      // N*128 bf16
    short* Wt    = h1b + (size_t)NNODES * 128;       // 57344 bf16
    float* stats = (float*)(Wt + 57344);             // 256 f32
    int* rowptr  = (int*)(stats + 256);              // N+1
    int* pos     = rowptr + (NNODES + 1);            // N
    int* elist   = pos + NNODES;                     // E
    int* bsums   = elist + NEDGES;                   // 128

    const short* W1t  = Wt;
    const short* W2t  = Wt + 16384;
    const short* Wm1t = Wt + 32768;
    const short* Wm2t = Wt + 49152;

    int gE = (NEDGES + 255) / 256;
    int gN = (NNODES + 255) / 256;

    k_init<<<gN, 256, 0, stream>>>(pos, stats);
    k_wconv<<<224, 256, 0, stream>>>(W1, W2, Wm1, Wm2, Wt);
    k_xb<<<(NNODES * 16 + 255) / 256, 256, 0, stream>>>(x, xb, NNODES * 16);
    k_hist<<<gE, 256, 0, stream>>>(ei, pos);
    k_scan1<<<SCAN_NB, 256, 0, stream>>>(pos, bsums);
    k_scan2<<<1, 64, 0, stream>>>(bsums, rowptr);
    k_scan3<<<SCAN_NB, 256, 0, stream>>>(pos, bsums, rowptr, pos);
    k_fill<<<gE, 256, 0, stream>>>(ei, pos, elist);
    k_agg<<<(NNODES + 3) / 4, 256, 0, stream>>>(xb, rowptr, elist, bufb);

    int nblk = (NNODES + 127) / 128;
    k_gemm1<<<nblk, 256, 0, stream>>>(bufb, W1t, b1, h1b, stats);
    k_mlp<<<nblk, 256, 0, stream>>>(h1b, stats, gamma, beta, W2t, b2, Wm1t, bm1, Wm2t, bm2, out);
}

// Round 4
// 193.995 us; speedup vs baseline: 6.4434x; 1.2127x over previous
//
#include <hip/hip_runtime.h>
#include <hip/hip_bf16.h>
#include <stdint.h>

#define NNODES 100000
#define NEDGES 600000
#define SCAN_CHUNK 1024
#define SCAN_NB 98  // ceil(100000/1024)

typedef __attribute__((ext_vector_type(8))) short bf16x8;
typedef __attribute__((ext_vector_type(4))) float f32x4;

__device__ inline float b2f(short b) {
    union { unsigned u; float f; } v;
    v.u = ((unsigned)(unsigned short)b) << 16;
    return v.f;
}
__device__ inline short f2b(float f) {
    union { float f; unsigned u; } v;
    v.f = f;
    unsigned r = (v.u + 0x7FFFu + ((v.u >> 16) & 1u)) >> 16;
    return (short)r;
}
// LDS XOR swizzle: bank-conflict-free ds_read_b128 of row-major [row][128*2B] bf16 tiles
__device__ inline int swz(int row, int kbyte) {
    return (row * 256 + kbyte) ^ ((row & 7) << 4);
}
#define MFMA16(a, b, c) __builtin_amdgcn_mfma_f32_16x16x32_bf16(a, b, c, 0, 0, 0)

// ---------------- fused prep: zero pos/stats, weights->bf16^T, x->bf16 (+zero row) ----
__global__ __launch_bounds__(256) void k_prep(const float* __restrict__ x,
                                              const float* __restrict__ W1,
                                              const float* __restrict__ W2,
                                              const float* __restrict__ Wm1,
                                              const float* __restrict__ Wm2,
                                              short* __restrict__ xb, short* __restrict__ Wt,
                                              int* __restrict__ pos, float* __restrict__ stats) {
    int i = blockIdx.x * 256 + threadIdx.x;
    if (i < (NNODES + 1) * 16) {
        bf16x8 o = (bf16x8){0, 0, 0, 0, 0, 0, 0, 0};
        if (i < NNODES * 16) {
            const float4* p = (const float4*)(x + (size_t)i * 8);
            float4 a = p[0], b = p[1];
            o[0] = f2b(a.x); o[1] = f2b(a.y); o[2] = f2b(a.z); o[3] = f2b(a.w);
            o[4] = f2b(b.x); o[5] = f2b(b.y); o[6] = f2b(b.z); o[7] = f2b(b.w);
        }
        *(bf16x8*)(xb + (size_t)i * 8) = o;
    }
    if (i < NNODES) pos[i] = 0;
    if (i < 57344) {
        float v;
        if (i < 16384) {
            int c = i >> 7, k = i & 127;
            v = W1[k * 128 + c];
        } else if (i < 32768) {
            int j = i - 16384;
            int c = j >> 7, k = j & 127;
            v = W2[k * 128 + c];
        } else if (i < 49152) {
            int j = i - 32768;
            int c = j >> 7, k = j & 127;
            v = Wm1[k * 128 + c];
        } else {
            int j = i - 49152;
            int c = j >> 7, k = j & 127;
            v = Wm2[k * 64 + c];
        }
        Wt[i] = f2b(v);
    }
    if (i < 256) stats[i] = 0.0f;
}

// ---------------- CSR build ----------------

__global__ __launch_bounds__(256) void k_hist(const int* __restrict__ ei, int* __restrict__ cnt) {
    int e = blockIdx.x * 256 + threadIdx.x;
    if (e < NEDGES) atomicAdd(&cnt[ei[NEDGES + e]], 1);
}

__global__ __launch_bounds__(256) void k_scan1(const int* __restrict__ cnt, int* __restrict__ bsums) {
    __shared__ int sd[256];
    int b = blockIdx.x, t = threadIdx.x;
    int base = b * SCAN_CHUNK + t * 4;
    int s = 0;
#pragma unroll
    for (int i = 0; i < 4; ++i) {
        int idx = base + i;
        if (idx < NNODES) s += cnt[idx];
    }
    sd[t] = s;
    __syncthreads();
    for (int off = 128; off > 0; off >>= 1) {
        if (t < off) sd[t] += sd[t + off];
        __syncthreads();
    }
    if (t == 0) bsums[b] = sd[0];
}

__global__ __launch_bounds__(64) void k_scan2(int* __restrict__ bsums, int* __restrict__ rowptr) {
    if (threadIdx.x == 0 && blockIdx.x == 0) {
        int run = 0;
        for (int b = 0; b < SCAN_NB; ++b) {
            int v = bsums[b];
            bsums[b] = run;
            run += v;
        }
        rowptr[NNODES] = run;
    }
}

__global__ __launch_bounds__(256) void k_scan3(const int* __restrict__ cnt,
                                               const int* __restrict__ bsums,
                                               int* __restrict__ rowptr, int* __restrict__ pos) {
    __shared__ int sd[256];
    int b = blockIdx.x, t = threadIdx.x;
    int base = b * SCAN_CHUNK + t * 4;
    int v[4];
    int s = 0;
#pragma unroll
    for (int i = 0; i < 4; ++i) {
        int idx = base + i;
        v[i] = (idx < NNODES) ? cnt[idx] : 0;
        s += v[i];
    }
    sd[t] = s;
    __syncthreads();
    for (int off = 1; off < 256; off <<= 1) {
        int val = (t >= off) ? sd[t - off] : 0;
        __syncthreads();
        sd[t] += val;
        __syncthreads();
    }
    int run = sd[t] - s + bsums[b];
#pragma unroll
    for (int i = 0; i < 4; ++i) {
        int idx = base + i;
        if (idx < NNODES) {
            rowptr[idx] = run;
            pos[idx] = run;
            run += v[i];
        }
    }
}

__global__ __launch_bounds__(256) void k_fill(const int* __restrict__ ei, int* __restrict__ pos,
                                              int* __restrict__ elist) {
    int e = blockIdx.x * 256 + threadIdx.x;
    if (e >= NEDGES) return;
    int src = ei[e];
    int dst = ei[NEDGES + e];
    int p = atomicAdd(&pos[dst], 1);
    elist[p] = src;
}

// ---------------- gather-aggregate, MLP-pipelined ----------------
// one wave per node. Wave halves gather two rows at once (8B/lane); up to 8 rows in
// flight per unrolled round. Entry j=0 is the node itself; out-of-range entries hit
// the zero row at xb[NNODES*128].
__global__ __launch_bounds__(256) void k_agg(const short* __restrict__ xb,
                                             const int* __restrict__ rowptr,
                                             const int* __restrict__ elist,
                                             short* __restrict__ bufb) {
    int t = threadIdx.x;
    int w = t >> 6, lane = t & 63;
    int node = blockIdx.x * 4 + w;
    if (node >= NNODES) return;
    int beg = rowptr[node];
    int end = rowptr[node + 1];
    int deg = end - beg;
    int total = deg + 1;
    int sub = lane & 31, half = lane >> 5;
    const uint2* xr = (const uint2*)xb;

    float acc0 = 0.f, acc1 = 0.f, acc2 = 0.f, acc3 = 0.f;

    for (int base = 0; base < total; base += 64) {
        int j = base + lane;
        int ej = NNODES;  // zero row
        if (j < total) ej = (j == 0) ? node : elist[beg + j - 1];
        int cnt = min(64, total - base);
        int pairs = (cnt + 1) >> 1;
        for (int i = 0; i < pairs; i += 4) {
            int j0 = 2 * i + half;
            int r0 = __shfl(ej, j0);
            int r1 = __shfl(ej, j0 + 2);
            int r2 = __shfl(ej, j0 + 4);
            int r3 = __shfl(ej, j0 + 6);
            uint2 v0 = xr[(size_t)r0 * 32 + sub];
            uint2 v1 = xr[(size_t)r1 * 32 + sub];
            uint2 v2 = xr[(size_t)r2 * 32 + sub];
            uint2 v3 = xr[(size_t)r3 * 32 + sub];
            acc0 += b2f((short)(v0.x & 0xFFFF)) + b2f((short)(v1.x & 0xFFFF)) +
                    b2f((short)(v2.x & 0xFFFF)) + b2f((short)(v3.x & 0xFFFF));
            acc1 += b2f((short)(v0.x >> 16)) + b2f((short)(v1.x >> 16)) +
                    b2f((short)(v2.x >> 16)) + b2f((short)(v3.x >> 16));
            acc2 += b2f((short)(v0.y & 0xFFFF)) + b2f((short)(v1.y & 0xFFFF)) +
                    b2f((short)(v2.y & 0xFFFF)) + b2f((short)(v3.y & 0xFFFF));
            acc3 += b2f((short)(v0.y >> 16)) + b2f((short)(v1.y >> 16)) +
                    b2f((short)(v2.y >> 16)) + b2f((short)(v3.y >> 16));
        }
    }
    acc0 += __shfl_xor(acc0, 32);
    acc1 += __shfl_xor(acc1, 32);
    acc2 += __shfl_xor(acc2, 32);
    acc3 += __shfl_xor(acc3, 32);
    if (half == 0) {
        uint2 o;
        o.x = ((uint32_t)(unsigned short)f2b(acc1) << 16) | (uint32_t)(unsigned short)f2b(acc0);
        o.y = ((uint32_t)(unsigned short)f2b(acc3) << 16) | (uint32_t)(unsigned short)f2b(acc2);
        ((uint2*)bufb)[(size_t)node * 32 + sub] = o;
    }
}

// ---------------- GEMM1 (MFMA) + BN stats ----------------
__global__ __launch_bounds__(256) void k_gemm1(const short* __restrict__ Ab,
                                               const short* __restrict__ W1t,
                                               const float* __restrict__ b1,
                                               short* __restrict__ h1b,
                                               float* __restrict__ stats) {
    __shared__ __align__(16) short act[128 * 128];
    __shared__ __align__(16) short wt[128 * 128];
    __shared__ float Sred[2][4][128];

    int t = threadIdx.x;
    int w = t >> 6, l = t & 63;
    int r0 = blockIdx.x * 128;

#pragma unroll
    for (int z = 0; z < 8; ++z) {
        int idx = t + z * 256;
        int row = idx >> 4, kc = idx & 15;
        int gr = r0 + row;
        bf16x8 v = (bf16x8){0, 0, 0, 0, 0, 0, 0, 0};
        if (gr < NNODES) v = *(const bf16x8*)(Ab + (size_t)gr * 128 + kc * 8);
        *(bf16x8*)((char*)act + swz(row, kc * 16)) = v;
    }
#pragma unroll
    for (int z = 0; z < 8; ++z) {
        int idx = t + z * 256;
        int row = idx >> 4, kc = idx & 15;
        *(bf16x8*)((char*)wt + swz(row, kc * 16)) =
            *(const bf16x8*)(W1t + (size_t)row * 128 + kc * 8);
    }
    __syncthreads();

    int row0 = (w & 1) * 64, col0 = (w >> 1) * 64;
    f32x4 acc[4][4];
#pragma unroll
    for (int r = 0; r < 4; ++r)
#pragma unroll
        for (int c = 0; c < 4; ++c) acc[r][c] = (f32x4){0.f, 0.f, 0.f, 0.f};

#pragma unroll
    for (int kb = 0; kb < 4; ++kb) {
        int kbyte = kb * 64 + (l >> 4) * 16;
        bf16x8 af[4], bw[4];
#pragma unroll
        for (int r = 0; r < 4; ++r)
            af[r] = *(const bf16x8*)((char*)act + swz(row0 + r * 16 + (l & 15), kbyte));
#pragma unroll
        for (int c = 0; c < 4; ++c)
            bw[c] = *(const bf16x8*)((char*)wt + swz(col0 + c * 16 + (l & 15), kbyte));
#pragma unroll
        for (int r = 0; r < 4; ++r)
#pragma unroll
            for (int c = 0; c < 4; ++c) acc[r][c] = MFMA16(af[r], bw[c], acc[r][c]);
    }

    float s[4], q[4];
#pragma unroll
    for (int c = 0; c < 4; ++c) { s[c] = 0.f; q[c] = 0.f; }
#pragma unroll
    for (int c = 0; c < 4; ++c) {
        float bias = b1[col0 + c * 16 + (l & 15)];
#pragma unroll
        for (int r = 0; r < 4; ++r)
#pragma unroll
            for (int rr = 0; rr < 4; ++rr) {
                float v = acc[r][c][rr] + bias;
                acc[r][c][rr] = v;
                int grow = r0 + row0 + r * 16 + (l >> 4) * 4 + rr;
                if (grow < NNODES) { s[c] += v; q[c] += v * v; }
            }
    }
#pragma unroll
    for (int c = 0; c < 4; ++c) {
        s[c] += __shfl_xor(s[c], 16); s[c] += __shfl_xor(s[c], 32);
        q[c] += __shfl_xor(q[c], 16); q[c] += __shfl_xor(q[c], 32);
    }
    if (l < 16) {
#pragma unroll
        for (int c = 0; c < 4; ++c) {
            Sred[0][w][col0 + c * 16 + l] = s[c];
            Sred[1][w][col0 + c * 16 + l] = q[c];
        }
    }
    __syncthreads();
    if (t < 128) {
        int wb = (t < 64) ? 0 : 2;
        atomicAdd(stats + t, Sred[0][wb][t] + Sred[0][wb + 1][t]);
        atomicAdd(stats + 128 + t, Sred[1][wb][t] + Sred[1][wb + 1][t]);
    }

#pragma unroll
    for (int r = 0; r < 4; ++r)
#pragma unroll
        for (int c = 0; c < 4; ++c)
#pragma unroll
            for (int rr = 0; rr < 4; ++rr) {
                int row = row0 + r * 16 + (l >> 4) * 4 + rr;
                int col = col0 + c * 16 + (l & 15);
                *(short*)((char*)act + swz(row, col * 2)) = f2b(acc[r][c][rr]);
            }
    __syncthreads();
#pragma unroll
    for (int z = 0; z < 8; ++z) {
        int idx = t + z * 256;
        int row = idx >> 4, kc = idx & 15;
        int gr = r0 + row;
        if (gr < NNODES)
            *(bf16x8*)(h1b + (size_t)gr * 128 + kc * 8) =
                *(const bf16x8*)((char*)act + swz(row, kc * 16));
    }
}

// ---------------- fused BN + ReLU + GEMM2 + ReLU + GEMM3 + ReLU + GEMM4 (MFMA) -------
__global__ __launch_bounds__(256) void k_mlp(const short* __restrict__ h1b,
                                             const float* __restrict__ stats,
                                             const float* __restrict__ gamma,
                                             const float* __restrict__ beta,
                                             const short* __restrict__ W2t,
                                             const float* __restrict__ b2,
                                             const short* __restrict__ Wm1t,
                                             const float* __restrict__ bm1,
                                             const short* __restrict__ Wm2t,
                                             const float* __restrict__ bm2,
                                             float* __restrict__ out) {
    __shared__ __align__(16) short act[128 * 128];
    __shared__ __align__(16) short wt[128 * 128];
    __shared__ float scale[128], shift[128];

    int t = threadIdx.x, w = t >> 6, l = t & 63;
    int r0 = blockIdx.x * 128;

    if (t < 128) {
        float mean = stats[t] * (1.0f / NNODES);
        float var = stats[128 + t] * (1.0f / NNODES) - mean * mean;
        var = fmaxf(var, 0.0f);
        float inv = rsqrtf(var + 1e-5f);
        float sc = gamma[t] * inv;
        scale[t] = sc;
        shift[t] = beta[t] - mean * sc;
    }
#pragma unroll
    for (int z = 0; z < 8; ++z) {
        int idx = t + z * 256;
        int row = idx >> 4, kc = idx & 15;
        *(bf16x8*)((char*)wt + swz(row, kc * 16)) =
            *(const bf16x8*)(W2t + (size_t)row * 128 + kc * 8);
    }
    __syncthreads();

#pragma unroll
    for (int z = 0; z < 8; ++z) {
        int idx = t + z * 256;
        int row = idx >> 4, kc = idx & 15;
        int gr = r0 + row;
        bf16x8 o = (bf16x8){0, 0, 0, 0, 0, 0, 0, 0};
        if (gr < NNODES) {
            bf16x8 v = *(const bf16x8*)(h1b + (size_t)gr * 128 + kc * 8);
#pragma unroll
            for (int j = 0; j < 8; ++j) {
                int k = kc * 8 + j;
                float f = b2f(v[j]) * scale[k] + shift[k];
                o[j] = f2b(fmaxf(f, 0.f));
            }
        }
        *(bf16x8*)((char*)act + swz(row, kc * 16)) = o;
    }
    __syncthreads();

    int row0 = (w & 1) * 64, col0 = (w >> 1) * 64;
    f32x4 acc[4][4];

    // ---- GEMM2 ----
#pragma unroll
    for (int r = 0; r < 4; ++r)
#pragma unroll
        for (int c = 0; c < 4; ++c) acc[r][c] = (f32x4){0.f, 0.f, 0.f, 0.f};
#pragma unroll
    for (int kb = 0; kb < 4; ++kb) {
        int kbyte = kb * 64 + (l >> 4) * 16;
        bf16x8 af[4], bw[4];
#pragma unroll
        for (int r = 0; r < 4; ++r)
            af[r] = *(const bf16x8*)((char*)act + swz(row0 + r * 16 + (l & 15), kbyte));
#pragma unroll
        for (int c = 0; c < 4; ++c)
            bw[c] = *(const bf16x8*)((char*)wt + swz(col0 + c * 16 + (l & 15), kbyte));
#pragma unroll
        for (int r = 0; r < 4; ++r)
#pragma unroll
            for (int c = 0; c < 4; ++c) acc[r][c] = MFMA16(af[r], bw[c], acc[r][c]);
    }
    __syncthreads();
#pragma unroll
    for (int c = 0; c < 4; ++c) {
        float bias = b2[col0 + c * 16 + (l & 15)];
#pragma unroll
        for (int r = 0; r < 4; ++r)
#pragma unroll
            for (int rr = 0; rr < 4; ++rr) {
                int row = row0 + r * 16 + (l >> 4) * 4 + rr;
                int col = col0 + c * 16 + (l & 15);
                *(short*)((char*)act + swz(row, col * 2)) = f2b(fmaxf(acc[r][c][rr] + bias, 0.f));
            }
    }
#pragma unroll
    for (int z = 0; z < 8; ++z) {
        int idx = t + z * 256;
        int row = idx >> 4, kc = idx & 15;
        *(bf16x8*)((char*)wt + swz(row, kc * 16)) =
            *(const bf16x8*)(Wm1t + (size_t)row * 128 + kc * 8);
    }
    __syncthreads();

    // ---- GEMM3 ----
#pragma unroll
    for (int r = 0; r < 4; ++r)
#pragma unroll
        for (int c = 0; c < 4; ++c) acc[r][c] = (f32x4){0.f, 0.f, 0.f, 0.f};
#pragma unroll
    for (int kb = 0; kb < 4; ++kb) {
        int kbyte = kb * 64 + (l >> 4) * 16;
        bf16x8 af[4], bw[4];
#pragma unroll
        for (int r = 0; r < 4; ++r)
            af[r] = *(const bf16x8*)((char*)act + swz(row0 + r * 16 + (l & 15), kbyte));
#pragma unroll
        for (int c = 0; c < 4; ++c)
            bw[c] = *(const bf16x8*)((char*)wt + swz(col0 + c * 16 + (l & 15), kbyte));
#pragma unroll
        for (int r = 0; r < 4; ++r)
#pragma unroll
            for (int c = 0; c < 4; ++c) acc[r][c] = MFMA16(af[r], bw[c], acc[r][c]);
    }
    __syncthreads();
#pragma unroll
    for (int c = 0; c < 4; ++c) {
        float bias = bm1[col0 + c * 16 + (l & 15)];
#pragma unroll
        for (int r = 0; r < 4; ++r)
#pragma unroll
            for (int rr = 0; rr < 4; ++rr) {
                int row = row0 + r * 16 + (l >> 4) * 4 + rr;
                int col = col0 + c * 16 + (l & 15);
                *(short*)((char*)act + swz(row, col * 2)) = f2b(fmaxf(acc[r][c][rr] + bias, 0.f));
            }
    }
#pragma unroll
    for (int z = 0; z < 4; ++z) {
        int idx = t + z * 256;
        int row = idx >> 4, kc = idx & 15;
        *(bf16x8*)((char*)wt + swz(row, kc * 16)) =
            *(const bf16x8*)(Wm2t + (size_t)row * 128 + kc * 8);
    }
    __syncthreads();

    // ---- GEMM4: [128 x 64] ----
    int row0q = w * 32;
    f32x4 a2[2][4];
#pragma unroll
    for (int r = 0; r < 2; ++r)
#pragma unroll
        for (int c = 0; c < 4; ++c) a2[r][c] = (f32x4){0.f, 0.f, 0.f, 0.f};
#pragma unroll
    for (int kb = 0; kb < 4; ++kb) {
        int kbyte = kb * 64 + (l >> 4) * 16;
        bf16x8 af[2], bw[4];
#pragma unroll
        for (int r = 0; r < 2; ++r)
            af[r] = *(const bf16x8*)((char*)act + swz(row0q + r * 16 + (l & 15), kbyte));
#pragma unroll
        for (int c = 0; c < 4; ++c)
            bw[c] = *(const bf16x8*)((char*)wt + swz(c * 16 + (l & 15), kbyte));
#pragma unroll
        for (int r = 0; r < 2; ++r)
#pragma unroll
            for (int c = 0; c < 4; ++c) a2[r][c] = MFMA16(af[r], bw[c], a2[r][c]);
    }
#pragma unroll
    for (int c = 0; c < 4; ++c) {
        float bias = bm2[c * 16 + (l & 15)];
#pragma unroll
        for (int r = 0; r < 2; ++r)
#pragma unroll
            for (int rr = 0; rr < 4; ++rr) {
                int grow = r0 + row0q + r * 16 + (l >> 4) * 4 + rr;
                if (grow < NNODES)
                    out[(size_t)grow * 64 + c * 16 + (l & 15)] = a2[r][c][rr] + bias;
            }
    }
}

// ---------------- launch ----------------
extern "C" void kernel_launch(void* const* d_in, const int* in_sizes, int n_in,
                              void* d_out, int out_size, void* d_ws, size_t ws_size,
                              hipStream_t stream) {
    const float* x     = (const float*)d_in[0];
    const int*   ei    = (const int*)d_in[1];
    const float* W1    = (const float*)d_in[2];
    const float* b1    = (const float*)d_in[3];
    const float* gamma = (const float*)d_in[4];
    const float* beta  = (const float*)d_in[5];
    const float* W2    = (const float*)d_in[6];
    const float* b2    = (const float*)d_in[7];
    const float* Wm1   = (const float*)d_in[8];
    const float* bm1   = (const float*)d_in[9];
    const float* Wm2   = (const float*)d_in[10];
    const float* bm2   = (const float*)d_in[11];
    float* out = (float*)d_out;

    char* ws = (char*)d_ws;
    short* xb    = (short*)ws;                         // (N+1)*128 bf16 (last row = zeros)
    short* bufb  = xb + (size_t)(NNODES + 1) * 128;    // N*128 bf16
    short* h1b   = bufb + (size_t)NNODES * 128;        // N*128 bf16
    short* Wt    = h1b + (size_t)NNODES * 128;         // 57344 bf16
    float* stats = (float*)(Wt + 57344);               // 256 f32
    int* rowptr  = (int*)(stats + 256);                // N+1
    int* pos     = rowptr + (NNODES + 1);              // N
    int* elist   = pos + NNODES;                       // E
    int* bsums   = elist + NEDGES;                     // 128

    const short* W1t  = Wt;
    const short* W2t  = Wt + 16384;
    const short* Wm1t = Wt + 32768;
    const short* Wm2t = Wt + 49152;

    int gE = (NEDGES + 255) / 256;
    int gPrep = ((NNODES + 1) * 16 + 255) / 256;

    k_prep<<<gPrep, 256, 0, stream>>>(x, W1, W2, Wm1, Wm2, xb, Wt, pos, stats);
    k_hist<<<gE, 256, 0, stream>>>(ei, pos);
    k_scan1<<<SCAN_NB, 256, 0, stream>>>(pos, bsums);
    k_scan2<<<1, 64, 0, stream>>>(bsums, rowptr);
    k_scan3<<<SCAN_NB, 256, 0, stream>>>(pos, bsums, rowptr, pos);
    k_fill<<<gE, 256, 0, stream>>>(ei, pos, elist);
    k_agg<<<(NNODES + 3) / 4, 256, 0, stream>>>(xb, rowptr, elist, bufb);

    int nblk = (NNODES + 127) / 128;
    k_gemm1<<<nblk, 256, 0, stream>>>(bufb, W1t, b1, h1b, stats);
    k_mlp<<<nblk, 256, 0, stream>>>(h1b, stats, gamma, beta, W2t, b2, Wm1t, bm1, Wm2t, bm2, out);
}

// Round 5
// 180.122 us; speedup vs baseline: 6.9397x; 1.0770x over previous
//
#include <hip/hip_runtime.h>
#include <hip/hip_bf16.h>
#include <stdint.h>

#define NNODES 100000
#define NEDGES 600000
#define SCAN_CHUNK 1024
#define SCAN_NB 98  // ceil(100000/1024)

typedef __attribute__((ext_vector_type(8))) short bf16x8;
typedef __attribute__((ext_vector_type(4))) float f32x4;

__device__ inline float b2f(short b) {
    union { unsigned u; float f; } v;
    v.u = ((unsigned)(unsigned short)b) << 16;
    return v.f;
}
__device__ inline short f2b(float f) {
    union { float f; unsigned u; } v;
    v.f = f;
    unsigned r = (v.u + 0x7FFFu + ((v.u >> 16) & 1u)) >> 16;
    return (short)r;
}
// LDS XOR swizzle: bank-conflict-free ds_read_b128 of row-major [row][128*2B] bf16 tiles
__device__ inline int swz(int row, int kbyte) {
    return (row * 256 + kbyte) ^ ((row & 7) << 4);
}
#define MFMA16(a, b, c) __builtin_amdgcn_mfma_f32_16x16x32_bf16(a, b, c, 0, 0, 0)

// ---------------- fused prep ----------------
// zero pos/stats; x->bf16 (+zero row); weights -> bf16 packed in per-lane MFMA
// B-fragment order: Wpk[kb][cb][lane][j]  (lane = ((k>>3)&3)*16 + (c&15), j = k&7)
__global__ __launch_bounds__(256) void k_prep(const float* __restrict__ x,
                                              const float* __restrict__ W1,
                                              const float* __restrict__ W2,
                                              const float* __restrict__ Wm1,
                                              const float* __restrict__ Wm2,
                                              short* __restrict__ xb, short* __restrict__ Wt,
                                              int* __restrict__ pos, float* __restrict__ stats) {
    int i = blockIdx.x * 256 + threadIdx.x;
    if (i < (NNODES + 1) * 16) {
        bf16x8 o = (bf16x8){0, 0, 0, 0, 0, 0, 0, 0};
        if (i < NNODES * 16) {
            const float4* p = (const float4*)(x + (size_t)i * 8);
            float4 a = p[0], b = p[1];
            o[0] = f2b(a.x); o[1] = f2b(a.y); o[2] = f2b(a.z); o[3] = f2b(a.w);
            o[4] = f2b(b.x); o[5] = f2b(b.y); o[6] = f2b(b.z); o[7] = f2b(b.w);
        }
        *(bf16x8*)(xb + (size_t)i * 8) = o;
    }
    if (i < NNODES) pos[i] = 0;
    if (i < 57344) {
        float v;
        int c, k, base, ncb;
        if (i < 16384) {
            c = i >> 7; k = i & 127; v = W1[k * 128 + c]; base = 0; ncb = 8;
        } else if (i < 32768) {
            int j = i - 16384; c = j >> 7; k = j & 127; v = W2[k * 128 + c]; base = 16384; ncb = 8;
        } else if (i < 49152) {
            int j = i - 32768; c = j >> 7; k = j & 127; v = Wm1[k * 128 + c]; base = 32768; ncb = 8;
        } else {
            int j = i - 49152; c = j >> 7; k = j & 127; v = Wm2[k * 64 + c]; base = 49152; ncb = 4;
        }
        int kb = k >> 5, hi = (k >> 3) & 3, jj = k & 7;
        int cb = c >> 4, lr = c & 15;
        int lane = hi * 16 + lr;
        int dst = base + (((kb * ncb) + cb) * 64 + lane) * 8 + jj;
        Wt[dst] = f2b(v);
    }
    if (i < 256) stats[i] = 0.0f;
}

// ---------------- CSR build ----------------

__global__ __launch_bounds__(256) void k_hist(const int* __restrict__ ei, int* __restrict__ cnt) {
    int e = blockIdx.x * 256 + threadIdx.x;
    if (e < NEDGES) atomicAdd(&cnt[ei[NEDGES + e]], 1);
}

__global__ __launch_bounds__(256) void k_scan1(const int* __restrict__ cnt, int* __restrict__ bsums) {
    __shared__ int sd[256];
    int b = blockIdx.x, t = threadIdx.x;
    int base = b * SCAN_CHUNK + t * 4;
    int s = 0;
#pragma unroll
    for (int i = 0; i < 4; ++i) {
        int idx = base + i;
        if (idx < NNODES) s += cnt[idx];
    }
    sd[t] = s;
    __syncthreads();
    for (int off = 128; off > 0; off >>= 1) {
        if (t < off) sd[t] += sd[t + off];
        __syncthreads();
    }
    if (t == 0) bsums[b] = sd[0];
}

__global__ __launch_bounds__(64) void k_scan2(int* __restrict__ bsums, int* __restrict__ rowptr) {
    if (threadIdx.x == 0 && blockIdx.x == 0) {
        int run = 0;
        for (int b = 0; b < SCAN_NB; ++b) {
            int v = bsums[b];
            bsums[b] = run;
            run += v;
        }
        rowptr[NNODES] = run;
    }
}

__global__ __launch_bounds__(256) void k_scan3(const int* __restrict__ cnt,
                                               const int* __restrict__ bsums,
                                               int* __restrict__ rowptr, int* __restrict__ pos) {
    __shared__ int sd[256];
    int b = blockIdx.x, t = threadIdx.x;
    int base = b * SCAN_CHUNK + t * 4;
    int v[4];
    int s = 0;
#pragma unroll
    for (int i = 0; i < 4; ++i) {
        int idx = base + i;
        v[i] = (idx < NNODES) ? cnt[idx] : 0;
        s += v[i];
    }
    sd[t] = s;
    __syncthreads();
    for (int off = 1; off < 256; off <<= 1) {
        int val = (t >= off) ? sd[t - off] : 0;
        __syncthreads();
        sd[t] += val;
        __syncthreads();
    }
    int run = sd[t] - s + bsums[b];
#pragma unroll
    for (int i = 0; i < 4; ++i) {
        int idx = base + i;
        if (idx < NNODES) {
            rowptr[idx] = run;
            pos[idx] = run;
            run += v[i];
        }
    }
}

__global__ __launch_bounds__(256) void k_fill(const int* __restrict__ ei, int* __restrict__ pos,
                                              int* __restrict__ elist) {
    int e = blockIdx.x * 256 + threadIdx.x;
    if (e >= NEDGES) return;
    int src = ei[e];
    int dst = ei[NEDGES + e];
    int p = atomicAdd(&pos[dst], 1);
    elist[p] = src;
}

// ---------------- gather-aggregate ----------------
__global__ __launch_bounds__(256) void k_agg(const short* __restrict__ xb,
                                             const int* __restrict__ rowptr,
                                             const int* __restrict__ elist,
                                             short* __restrict__ bufb) {
    int t = threadIdx.x;
    int w = t >> 6, lane = t & 63;
    int node = blockIdx.x * 4 + w;
    if (node >= NNODES) return;
    int beg = rowptr[node];
    int end = rowptr[node + 1];
    int deg = end - beg;
    int total = deg + 1;
    int sub = lane & 31, half = lane >> 5;
    const uint2* xr = (const uint2*)xb;

    float acc0 = 0.f, acc1 = 0.f, acc2 = 0.f, acc3 = 0.f;

    for (int base = 0; base < total; base += 64) {
        int j = base + lane;
        int ej = NNODES;  // zero row
        if (j < total) ej = (j == 0) ? node : elist[beg + j - 1];
        int cnt = min(64, total - base);
        int pairs = (cnt + 1) >> 1;
        for (int i = 0; i < pairs; i += 4) {
            int j0 = 2 * i + half;
            int r0 = __shfl(ej, j0);
            int r1 = __shfl(ej, j0 + 2);
            int r2 = __shfl(ej, j0 + 4);
            int r3 = __shfl(ej, j0 + 6);
            uint2 v0 = xr[(size_t)r0 * 32 + sub];
            uint2 v1 = xr[(size_t)r1 * 32 + sub];
            uint2 v2 = xr[(size_t)r2 * 32 + sub];
            uint2 v3 = xr[(size_t)r3 * 32 + sub];
            acc0 += b2f((short)(v0.x & 0xFFFF)) + b2f((short)(v1.x & 0xFFFF)) +
                    b2f((short)(v2.x & 0xFFFF)) + b2f((short)(v3.x & 0xFFFF));
            acc1 += b2f((short)(v0.x >> 16)) + b2f((short)(v1.x >> 16)) +
                    b2f((short)(v2.x >> 16)) + b2f((short)(v3.x >> 16));
            acc2 += b2f((short)(v0.y & 0xFFFF)) + b2f((short)(v1.y & 0xFFFF)) +
                    b2f((short)(v2.y & 0xFFFF)) + b2f((short)(v3.y & 0xFFFF));
            acc3 += b2f((short)(v0.y >> 16)) + b2f((short)(v1.y >> 16)) +
                    b2f((short)(v2.y >> 16)) + b2f((short)(v3.y >> 16));
        }
    }
    acc0 += __shfl_xor(acc0, 32);
    acc1 += __shfl_xor(acc1, 32);
    acc2 += __shfl_xor(acc2, 32);
    acc3 += __shfl_xor(acc3, 32);
    if (half == 0) {
        uint2 o;
        o.x = ((uint32_t)(unsigned short)f2b(acc1) << 16) | (uint32_t)(unsigned short)f2b(acc0);
        o.y = ((uint32_t)(unsigned short)f2b(acc3) << 16) | (uint32_t)(unsigned short)f2b(acc2);
        ((uint2*)bufb)[(size_t)node * 32 + sub] = o;
    }
}

// ---------------- stats: u = agg @ W1 (no bias; b1 cancels in BN); S,Q per col ------
__global__ __launch_bounds__(256) void k_stats(const short* __restrict__ bufb,
                                               const short* __restrict__ W1pk,
                                               float* __restrict__ stats) {
    __shared__ float Sred[2][4][128];
    int t = threadIdx.x, w = t >> 6, l = t & 63;
    int r0 = blockIdx.x * 128;
    int row0 = (w & 1) * 64, col0 = (w >> 1) * 64;

    f32x4 acc[4][4];
#pragma unroll
    for (int r = 0; r < 4; ++r)
#pragma unroll
        for (int c = 0; c < 4; ++c) acc[r][c] = (f32x4){0.f, 0.f, 0.f, 0.f};

#pragma unroll
    for (int kb = 0; kb < 4; ++kb) {
        bf16x8 af[4], bw[4];
#pragma unroll
        for (int r = 0; r < 4; ++r)
            af[r] = *(const bf16x8*)(bufb + (size_t)(r0 + row0 + r * 16 + (l & 15)) * 128 +
                                     kb * 32 + (l >> 4) * 8);
#pragma unroll
        for (int c = 0; c < 4; ++c)
            bw[c] = *(const bf16x8*)(W1pk + ((kb * 8 + (w >> 1) * 4 + c) * 64 + l) * 8);
#pragma unroll
        for (int r = 0; r < 4; ++r)
#pragma unroll
            for (int c = 0; c < 4; ++c) acc[r][c] = MFMA16(af[r], bw[c], acc[r][c]);
    }

    float s[4], q[4];
#pragma unroll
    for (int c = 0; c < 4; ++c) { s[c] = 0.f; q[c] = 0.f; }
#pragma unroll
    for (int c = 0; c < 4; ++c)
#pragma unroll
        for (int r = 0; r < 4; ++r)
#pragma unroll
            for (int rr = 0; rr < 4; ++rr) {
                int grow = r0 + row0 + r * 16 + (l >> 4) * 4 + rr;
                if (grow < NNODES) {
                    float v = acc[r][c][rr];
                    s[c] += v;
                    q[c] += v * v;
                }
            }
#pragma unroll
    for (int c = 0; c < 4; ++c) {
        s[c] += __shfl_xor(s[c], 16); s[c] += __shfl_xor(s[c], 32);
        q[c] += __shfl_xor(q[c], 16); q[c] += __shfl_xor(q[c], 32);
    }
    if (l < 16) {
#pragma unroll
        for (int c = 0; c < 4; ++c) {
            Sred[0][w][col0 + c * 16 + l] = s[c];
            Sred[1][w][col0 + c * 16 + l] = q[c];
        }
    }
    __syncthreads();
    if (t < 128) {
        int wb = (t < 64) ? 0 : 2;
        atomicAdd(stats + t, Sred[0][wb][t] + Sred[0][wb + 1][t]);
        atomicAdd(stats + 128 + t, Sred[1][wb][t] + Sred[1][wb + 1][t]);
    }
}

// ---------------- fused G1+BN+ReLU, G2+ReLU, G3+ReLU, G4 (all MFMA) ----------------
__global__ __launch_bounds__(256) void k_mlp(const short* __restrict__ bufb,
                                             const float* __restrict__ stats,
                                             const float* __restrict__ gamma,
                                             const float* __restrict__ beta,
                                             const short* __restrict__ Wt,
                                             const float* __restrict__ b2,
                                             const float* __restrict__ bm1,
                                             const float* __restrict__ bm2,
                                             float* __restrict__ out) {
    __shared__ __align__(16) short act[128 * 128];  // 32KB
    __shared__ float scale[128], shift[128];

    int t = threadIdx.x, w = t >> 6, l = t & 63;
    int r0 = blockIdx.x * 128;
    const short* W1pk = Wt;
    const short* W2pk = Wt + 16384;
    const short* Wm1pk = Wt + 32768;
    const short* Wm2pk = Wt + 49152;

    if (t < 128) {
        float mean = stats[t] * (1.0f / NNODES);
        float var = stats[128 + t] * (1.0f / NNODES) - mean * mean;
        var = fmaxf(var, 0.0f);
        float inv = rsqrtf(var + 1e-5f);
        float sc = gamma[t] * inv;
        scale[t] = sc;
        shift[t] = beta[t] - mean * sc;  // b1 cancels in batch-stats BN
    }
    __syncthreads();

    int row0 = (w & 1) * 64, col0 = (w >> 1) * 64;
    f32x4 acc[4][4];

    // ---- G1: A direct from global, B = W1pk; epilogue BN+ReLU -> act ----
#pragma unroll
    for (int r = 0; r < 4; ++r)
#pragma unroll
        for (int c = 0; c < 4; ++c) acc[r][c] = (f32x4){0.f, 0.f, 0.f, 0.f};
#pragma unroll
    for (int kb = 0; kb < 4; ++kb) {
        bf16x8 af[4], bw[4];
#pragma unroll
        for (int r = 0; r < 4; ++r)
            af[r] = *(const bf16x8*)(bufb + (size_t)(r0 + row0 + r * 16 + (l & 15)) * 128 +
                                     kb * 32 + (l >> 4) * 8);
#pragma unroll
        for (int c = 0; c < 4; ++c)
            bw[c] = *(const bf16x8*)(W1pk + ((kb * 8 + (w >> 1) * 4 + c) * 64 + l) * 8);
#pragma unroll
        for (int r = 0; r < 4; ++r)
#pragma unroll
            for (int c = 0; c < 4; ++c) acc[r][c] = MFMA16(af[r], bw[c], acc[r][c]);
    }
#pragma unroll
    for (int c = 0; c < 4; ++c) {
        int col = col0 + c * 16 + (l & 15);
        float sc_ = scale[col], sh_ = shift[col];
#pragma unroll
        for (int r = 0; r < 4; ++r)
#pragma unroll
            for (int rr = 0; rr < 4; ++rr) {
                int row = row0 + r * 16 + (l >> 4) * 4 + rr;
                *(short*)((char*)act + swz(row, col * 2)) =
                    f2b(fmaxf(acc[r][c][rr] * sc_ + sh_, 0.f));
            }
    }
    __syncthreads();

    // ---- G2: A from act LDS, B = W2pk; +b2, ReLU ----
#pragma unroll
    for (int r = 0; r < 4; ++r)
#pragma unroll
        for (int c = 0; c < 4; ++c) acc[r][c] = (f32x4){0.f, 0.f, 0.f, 0.f};
#pragma unroll
    for (int kb = 0; kb < 4; ++kb) {
        int kbyte = kb * 64 + (l >> 4) * 16;
        bf16x8 af[4], bw[4];
#pragma unroll
        for (int r = 0; r < 4; ++r)
            af[r] = *(const bf16x8*)((char*)act + swz(row0 + r * 16 + (l & 15), kbyte));
#pragma unroll
        for (int c = 0; c < 4; ++c)
            bw[c] = *(const bf16x8*)(W2pk + ((kb * 8 + (w >> 1) * 4 + c) * 64 + l) * 8);
#pragma unroll
        for (int r = 0; r < 4; ++r)
#pragma unroll
            for (int c = 0; c < 4; ++c) acc[r][c] = MFMA16(af[r], bw[c], acc[r][c]);
    }
    __syncthreads();
#pragma unroll
    for (int c = 0; c < 4; ++c) {
        int col = col0 + c * 16 + (l & 15);
        float bias = b2[col];
#pragma unroll
        for (int r = 0; r < 4; ++r)
#pragma unroll
            for (int rr = 0; rr < 4; ++rr) {
                int row = row0 + r * 16 + (l >> 4) * 4 + rr;
                *(short*)((char*)act + swz(row, col * 2)) = f2b(fmaxf(acc[r][c][rr] + bias, 0.f));
            }
    }
    __syncthreads();

    // ---- G3: B = Wm1pk; +bm1, ReLU ----
#pragma unroll
    for (int r = 0; r < 4; ++r)
#pragma unroll
        for (int c = 0; c < 4; ++c) acc[r][c] = (f32x4){0.f, 0.f, 0.f, 0.f};
#pragma unroll
    for (int kb = 0; kb < 4; ++kb) {
        int kbyte = kb * 64 + (l >> 4) * 16;
        bf16x8 af[4], bw[4];
#pragma unroll
        for (int r = 0; r < 4; ++r)
            af[r] = *(const bf16x8*)((char*)act + swz(row0 + r * 16 + (l & 15), kbyte));
#pragma unroll
        for (int c = 0; c < 4; ++c)
            bw[c] = *(const bf16x8*)(Wm1pk + ((kb * 8 + (w >> 1) * 4 + c) * 64 + l) * 8);
#pragma unroll
        for (int r = 0; r < 4; ++r)
#pragma unroll
            for (int c = 0; c < 4; ++c) acc[r][c] = MFMA16(af[r], bw[c], acc[r][c]);
    }
    __syncthreads();
#pragma unroll
    for (int c = 0; c < 4; ++c) {
        int col = col0 + c * 16 + (l & 15);
        float bias = bm1[col];
#pragma unroll
        for (int r = 0; r < 4; ++r)
#pragma unroll
            for (int rr = 0; rr < 4; ++rr) {
                int row = row0 + r * 16 + (l >> 4) * 4 + rr;
                *(short*)((char*)act + swz(row, col * 2)) = f2b(fmaxf(acc[r][c][rr] + bias, 0.f));
            }
    }
    __syncthreads();

    // ---- G4: [128 x 64], B = Wm2pk; +bm2 -> out ----
    int row0q = w * 32;
    f32x4 a2[2][4];
#pragma unroll
    for (int r = 0; r < 2; ++r)
#pragma unroll
        for (int c = 0; c < 4; ++c) a2[r][c] = (f32x4){0.f, 0.f, 0.f, 0.f};
#pragma unroll
    for (int kb = 0; kb < 4; ++kb) {
        int kbyte = kb * 64 + (l >> 4) * 16;
        bf16x8 af[2], bw[4];
#pragma unroll
        for (int r = 0; r < 2; ++r)
            af[r] = *(const bf16x8*)((char*)act + swz(row0q + r * 16 + (l & 15), kbyte));
#pragma unroll
        for (int c = 0; c < 4; ++c)
            bw[c] = *(const bf16x8*)(Wm2pk + ((kb * 4 + c) * 64 + l) * 8);
#pragma unroll
        for (int r = 0; r < 2; ++r)
#pragma unroll
            for (int c = 0; c < 4; ++c) a2[r][c] = MFMA16(af[r], bw[c], a2[r][c]);
    }
#pragma unroll
    for (int c = 0; c < 4; ++c) {
        float bias = bm2[c * 16 + (l & 15)];
#pragma unroll
        for (int r = 0; r < 2; ++r)
#pragma unroll
            for (int rr = 0; rr < 4; ++rr) {
                int grow = r0 + row0q + r * 16 + (l >> 4) * 4 + rr;
                if (grow < NNODES)
                    out[(size_t)grow * 64 + c * 16 + (l & 15)] = a2[r][c][rr] + bias;
            }
    }
}

// ---------------- launch ----------------
extern "C" void kernel_launch(void* const* d_in, const int* in_sizes, int n_in,
                              void* d_out, int out_size, void* d_ws, size_t ws_size,
                              hipStream_t stream) {
    const float* x     = (const float*)d_in[0];
    const int*   ei    = (const int*)d_in[1];
    const float* W1    = (const float*)d_in[2];
    const float* gamma = (const float*)d_in[4];
    const float* beta  = (const float*)d_in[5];
    const float* W2    = (const float*)d_in[6];
    const float* b2    = (const float*)d_in[7];
    const float* Wm1   = (const float*)d_in[8];
    const float* bm1   = (const float*)d_in[9];
    const float* Wm2   = (const float*)d_in[10];
    const float* bm2   = (const float*)d_in[11];
    float* out = (float*)d_out;

    char* ws = (char*)d_ws;
    short* xb    = (short*)ws;                           // (N+1)*128 bf16 (last row zeros)
    short* bufb  = xb + (size_t)(NNODES + 1) * 128;      // (N+128)*128 bf16 (tail padding)
    short* Wt    = bufb + (size_t)(NNODES + 128) * 128;  // 57344 bf16 packed fragments
    float* stats = (float*)(Wt + 57344);                 // 256 f32
    int* rowptr  = (int*)(stats + 256);                  // N+1
    int* pos     = rowptr + (NNODES + 1);                // N
    int* elist   = pos + NNODES;                         // E
    int* bsums   = elist + NEDGES;                       // 128

    int gE = (NEDGES + 255) / 256;
    int gPrep = ((NNODES + 1) * 16 + 255) / 256;

    k_prep<<<gPrep, 256, 0, stream>>>(x, W1, W2, Wm1, Wm2, xb, Wt, pos, stats);
    k_hist<<<gE, 256, 0, stream>>>(ei, pos);
    k_scan1<<<SCAN_NB, 256, 0, stream>>>(pos, bsums);
    k_scan2<<<1, 64, 0, stream>>>(bsums, rowptr);
    k_scan3<<<SCAN_NB, 256, 0, stream>>>(pos, bsums, rowptr, pos);
    k_fill<<<gE, 256, 0, stream>>>(ei, pos, elist);
    k_agg<<<(NNODES + 3) / 4, 256, 0, stream>>>(xb, rowptr, elist, bufb);

    int nblk = (NNODES + 127) / 128;
    k_stats<<<nblk, 256, 0, stream>>>(bufb, Wt, stats);
    k_mlp<<<nblk, 256, 0, stream>>>(bufb, stats, gamma, beta, Wt, b2, bm1, bm2, out);
}